// Round 1
// baseline (9584.093 us; speedup 1.0000x reference)
//
#include <hip/hip_runtime.h>

// Problem constants: B=64, S=128, D=512, T=64
// ws layout (float offsets):
//   Uk   [B*S*D]   = 4194304 @ 0
//   WhhT [512*1536]= 786432  @ 4194304   (WhhT[k*1536+j] = W_hh[j*512+k])
//   WihT [515*1536]= 791040  @ 4980736   (WihT[k*1536+j] = W_ih[j*515+k])
//   q    [64*512]  = 32768   @ 5771776
//   gh   [64*1536] = 98304   @ 5804544
//   ctx  [64*512]  = 32768   @ 5902848
//   h    [64*512]  = 32768   @ 5935616
//   bar  (2 x u32)           @ 5968384
// total ~23.9 MB of d_ws.

#define OFF_WHHT 4194304
#define OFF_WIHT 4980736
#define OFF_Q    5771776
#define OFF_GH   5804544
#define OFF_CTX  5902848
#define OFF_H    5935616
#define OFF_BAR  5968384

// ---------------- device-wide barrier (sense via generation counter) ----------------
__device__ __forceinline__ void grid_barrier(unsigned* cnt, unsigned* gen, unsigned nb) {
    __syncthreads();                      // all block stores issued & complete (vmcnt drained)
    if (threadIdx.x == 0) {
        __threadfence();                  // agent release: write back L2 so other XCDs see our data
        unsigned g = __hip_atomic_load(gen, __ATOMIC_RELAXED, __HIP_MEMORY_SCOPE_AGENT);
        unsigned old = __hip_atomic_fetch_add(cnt, 1u, __ATOMIC_ACQ_REL, __HIP_MEMORY_SCOPE_AGENT);
        if (old == nb - 1u) {
            __hip_atomic_store(cnt, 0u, __ATOMIC_RELAXED, __HIP_MEMORY_SCOPE_AGENT);
            __hip_atomic_fetch_add(gen, 1u, __ATOMIC_RELEASE, __HIP_MEMORY_SCOPE_AGENT);
        } else {
            while (__hip_atomic_load(gen, __ATOMIC_ACQUIRE, __HIP_MEMORY_SCOPE_AGENT) == g) {
                __builtin_amdgcn_s_sleep(1);
            }
        }
    }
    __syncthreads();
}

// ---------------- prep: Uk GEMM + weight transposes + h0 + barrier init ----------------
__global__ __launch_bounds__(256) void prep_kernel(
    const float* __restrict__ e_all, const float* __restrict__ e_last,
    const float* __restrict__ Ua_w,  const float* __restrict__ Ua_b,
    const float* __restrict__ W_ih,  const float* __restrict__ W_hh,
    float* __restrict__ ws)
{
    float* Uk   = ws;
    float* WhhT = ws + OFF_WHHT;
    float* WihT = ws + OFF_WIHT;
    float* h    = ws + OFF_H;

    __shared__ float a_s[16 * 512];       // 16 rows of e_all (rows = flattened (b,s))
    const int blk = blockIdx.x;           // 512 blocks, 16 rows each -> 8192 rows
    const int tid = threadIdx.x;

    if (blk == 0 && tid == 0) {
        unsigned* bar = (unsigned*)(ws + OFF_BAR);
        bar[0] = 0u; bar[1] = 0u;
    }

    const int r0 = blk * 16;
    for (int i = tid; i < 16 * 512; i += 256) a_s[i] = e_all[(size_t)r0 * 512 + i];
    __syncthreads();

    const int jj = tid & 63, sub = tid >> 6;     // sub 0..3 -> rows sub*4..sub*4+3
    const int rbase = sub * 4 * 512;
    for (int jo = 0; jo < 8; ++jo) {
        const int j = jo * 64 + jj;
        float a0 = 0.f, a1 = 0.f, a2 = 0.f, a3 = 0.f;
        const float* wp = Ua_w + j;
        #pragma unroll 2
        for (int k = 0; k < 512; ++k) {
            const float w = *wp; wp += 512;
            a0 = fmaf(w, a_s[rbase + k],        a0);
            a1 = fmaf(w, a_s[rbase + 512 + k],  a1);
            a2 = fmaf(w, a_s[rbase + 1024 + k], a2);
            a3 = fmaf(w, a_s[rbase + 1536 + k], a3);
        }
        const float bb = Ua_b[j];
        const int r = r0 + sub * 4;
        Uk[(size_t)(r + 0) * 512 + j] = a0 + bb;
        Uk[(size_t)(r + 1) * 512 + j] = a1 + bb;
        Uk[(size_t)(r + 2) * 512 + j] = a2 + bb;
        Uk[(size_t)(r + 3) * 512 + j] = a3 + bb;
    }

    // transposes + h0 (grid-stride)
    const int gtid = blk * 256 + tid;
    const int gstride = 512 * 256;
    for (int i = gtid; i < 512 * 1536; i += gstride) {
        const int k = i / 1536, j = i - k * 1536;
        WhhT[i] = W_hh[(size_t)j * 512 + k];
    }
    for (int i = gtid; i < 515 * 1536; i += gstride) {
        const int k = i / 1536, j = i - k * 1536;
        WihT[i] = W_ih[(size_t)j * 515 + k];
    }
    for (int i = gtid; i < 64 * 512; i += gstride) h[i] = e_last[i];
}

// ---------------- persistent decode loop: 64 blocks x 1024 threads ----------------
__global__ __launch_bounds__(1024) void decode_kernel(
    const float* __restrict__ e_all,
    const float* __restrict__ Wa_w, const float* __restrict__ Wa_b,
    const float* __restrict__ Va_w, const float* __restrict__ Va_b,
    const float* __restrict__ b_ih, const float* __restrict__ b_hh,
    const float* __restrict__ Wo_w, const float* __restrict__ Wo_b,
    float* __restrict__ out, float* __restrict__ ws)
{
    float* Uk   = ws;
    float* WhhT = ws + OFF_WHHT;
    float* WihT = ws + OFF_WIHT;
    float* q    = ws + OFF_Q;
    float* gh   = ws + OFF_GH;
    float* ctx  = ws + OFF_CTX;
    float* h    = ws + OFF_H;
    unsigned* bar = (unsigned*)(ws + OFF_BAR);

    __shared__ float smem[16384 + 64];

    const int tid  = threadIdx.x;
    const int blk  = blockIdx.x;          // 64 blocks
    const int jj   = tid & 63;
    const int sub  = tid >> 6;            // 0..15
    const int lane = tid & 63;
    const int wv   = tid >> 6;

    for (int t = 0; t < 64; ++t) {
        // ======== Phase A: q = h@Wa + Wa_b ; gh = h@W_hh^T + b_hh ; out[:,t-1] ========
        {
            const int m   = blk >> 5;     // b-half
            const int cgp = blk & 31;     // column group (0..7 -> q, 8..31 -> gh)
            for (int i = tid; i < 32 * 512; i += 1024) smem[i] = h[m * (32 * 512) + i];
            __syncthreads();

            const int b0 = sub * 2;       // local row pair
            const float* hp = smem + b0 * 512;
            float acc0 = 0.f, acc1 = 0.f;
            int jout, stride; const float* wp;
            if (cgp < 8) { jout = cgp * 64 + jj;       wp = Wa_w + jout; stride = 512; }
            else         { jout = (cgp - 8) * 64 + jj; wp = WhhT + jout; stride = 1536; }
            #pragma unroll 4
            for (int k = 0; k < 512; ++k) {
                const float w = *wp; wp += stride;
                acc0 = fmaf(w, hp[k],       acc0);
                acc1 = fmaf(w, hp[512 + k], acc1);
            }
            const int bg = m * 32 + b0;
            if (cgp < 8) {
                const float bb = Wa_b[jout];
                q[(size_t)bg * 512 + jout]       = acc0 + bb;
                q[(size_t)(bg + 1) * 512 + jout] = acc1 + bb;
            } else {
                const float bb = b_hh[jout];
                gh[(size_t)bg * 1536 + jout]       = acc0 + bb;
                gh[(size_t)(bg + 1) * 1536 + jout] = acc1 + bb;
            }
            // out[blk, t-1] = h[blk]@Wo + Wo_b   (h_lds local row cgp == blk - m*32)
            if (t > 0) {
                float p0 = 0.f, p1 = 0.f, p2 = 0.f;
                if (tid < 512) {
                    const float hv = smem[cgp * 512 + tid];
                    p0 = hv * Wo_w[tid * 3 + 0];
                    p1 = hv * Wo_w[tid * 3 + 1];
                    p2 = hv * Wo_w[tid * 3 + 2];
                }
                #pragma unroll
                for (int off = 32; off > 0; off >>= 1) {
                    p0 += __shfl_down(p0, off);
                    p1 += __shfl_down(p1, off);
                    p2 += __shfl_down(p2, off);
                }
                float* red = smem + 16384;
                if (lane == 0 && wv < 8) { red[wv * 3] = p0; red[wv * 3 + 1] = p1; red[wv * 3 + 2] = p2; }
                __syncthreads();
                if (tid < 3) {
                    float s_ = Wo_b[tid];
                    for (int w2 = 0; w2 < 8; ++w2) s_ += red[w2 * 3 + tid];
                    out[((size_t)blk * 64 + (t - 1)) * 3 + tid] = s_;
                }
            }
        }
        grid_barrier(bar, bar + 1, 64);

        // ======== Phase B: scores -> softmax -> w (cross_attn out) -> ctx, one block per b ========
        {
            const int b = blk;
            float* q_s  = smem;
            float* va_s = smem + 512;
            float* sc_s = smem + 1024;   // 128
            float* w_s  = smem + 1152;   // 128
            float* red  = smem + 1280;   // 2
            float* ctxp = smem + 1312;   // 512
            if (tid < 512) { q_s[tid] = q[(size_t)b * 512 + tid]; va_s[tid] = Va_w[tid]; }
            __syncthreads();

            #pragma unroll
            for (int so = 0; so < 8; ++so) {
                const int s = so * 16 + wv;
                const float* ukp = Uk + ((size_t)b * 128 + s) * 512;
                float acc = 0.f;
                #pragma unroll
                for (int ko = 0; ko < 8; ++ko) {
                    const int k = ko * 64 + lane;
                    float x = q_s[k] + ukp[k];
                    x = fminf(fmaxf(x, -15.f), 15.f);
                    const float e = __expf(-2.f * x);
                    acc = fmaf((1.f - e) / (1.f + e), va_s[k], acc);
                }
                #pragma unroll
                for (int off = 32; off > 0; off >>= 1) acc += __shfl_down(acc, off);
                if (lane == 0) sc_s[s] = acc;   // Va_b is a uniform shift; softmax-invariant
            }
            __syncthreads();
            if (tid < 64) {
                float mx = fmaxf(sc_s[tid], sc_s[tid + 64]);
                #pragma unroll
                for (int off = 32; off > 0; off >>= 1) mx = fmaxf(mx, __shfl_down(mx, off));
                if (tid == 0) red[0] = mx;
            }
            __syncthreads();
            if (tid < 128) w_s[tid] = __expf(sc_s[tid] - red[0]);
            __syncthreads();
            if (tid < 64) {
                float sm = w_s[tid] + w_s[tid + 64];
                #pragma unroll
                for (int off = 32; off > 0; off >>= 1) sm += __shfl_down(sm, off);
                if (tid == 0) red[1] = 1.f / sm;
            }
            __syncthreads();
            if (tid < 128) {
                const float wn = w_s[tid] * red[1];
                w_s[tid] = wn;
                out[45056 + ((size_t)b * 64 + t) * 128 + tid] = wn;   // cross_attn
            }
            __syncthreads();
            // ctx[b,d] = sum_s w[s] * e_all[b,s,d]  (s split in halves across tid>>9)
            {
                const int dd = tid & 511, half = tid >> 9;
                float acc = 0.f;
                const float* ep = e_all + ((size_t)b * 128 + half * 64) * 512 + dd;
                #pragma unroll 4
                for (int s2 = 0; s2 < 64; ++s2) acc = fmaf(w_s[half * 64 + s2], ep[(size_t)s2 * 512], acc);
                if (half == 1) ctxp[dd] = acc;
                __syncthreads();
                if (half == 0) ctx[(size_t)b * 512 + dd] = acc + ctxp[dd];
            }
        }
        grid_barrier(bar, bar + 1, 64);

        // ======== Phase C: gi = [ctx,x]@W_ih^T + b_ih ; GRU gates ; h in-place ========
        {
            const int bgp = blk >> 3;          // 8 groups of 8 b
            const int dg  = blk & 7;           // d group
            const int b0 = bgp * 8, d0 = dg * 64;
            float* ctx_s = smem;               // 8*512
            float* x_s   = smem + 4096;        // 24
            float* part  = smem + 4128;        // 8*64*3
            for (int i = tid; i < 8 * 512; i += 1024) ctx_s[i] = ctx[(size_t)b0 * 512 + i];
            if (tid < 24) {
                const int bb = tid / 3, c = tid - bb * 3;
                x_s[tid] = (t == 0) ? 0.f : out[((size_t)(b0 + bb) * 64 + (t - 1)) * 3 + c];
            }
            __syncthreads();

            const int lb = sub & 7, ks = sub >> 3;
            const int b = b0 + lb, d = d0 + jj;
            float aR = 0.f, aZ = 0.f, aN = 0.f;
            {
                const float* wp = WihT + (size_t)(ks * 256) * 1536 + d;
                const float* cp = ctx_s + lb * 512 + ks * 256;
                #pragma unroll 2
                for (int k = 0; k < 256; ++k) {
                    const float c = cp[k];
                    aR = fmaf(c, wp[0],    aR);
                    aZ = fmaf(c, wp[512],  aZ);
                    aN = fmaf(c, wp[1024], aN);
                    wp += 1536;
                }
            }
            if (ks == 0) {
                const float* wx = WihT + (size_t)512 * 1536 + d;
                #pragma unroll
                for (int c = 0; c < 3; ++c) {
                    const float xv = x_s[lb * 3 + c];
                    aR = fmaf(xv, wx[0],    aR);
                    aZ = fmaf(xv, wx[512],  aZ);
                    aN = fmaf(xv, wx[1024], aN);
                    wx += 1536;
                }
                aR += b_ih[d]; aZ += b_ih[512 + d]; aN += b_ih[1024 + d];
            } else {
                const int pi = (lb * 64 + jj) * 3;
                part[pi] = aR; part[pi + 1] = aZ; part[pi + 2] = aN;
            }
            __syncthreads();
            if (ks == 0) {
                const int pi = (lb * 64 + jj) * 3;
                aR += part[pi]; aZ += part[pi + 1]; aN += part[pi + 2];
                const float ghR = gh[(size_t)b * 1536 + d];
                const float ghZ = gh[(size_t)b * 1536 + 512 + d];
                const float ghN = gh[(size_t)b * 1536 + 1024 + d];
                const float r = 1.f / (1.f + __expf(-(aR + ghR)));
                const float z = 1.f / (1.f + __expf(-(aZ + ghZ)));
                float pre = aN + r * ghN;
                pre = fminf(fmaxf(pre, -15.f), 15.f);
                const float e2 = __expf(-2.f * pre);
                const float n = (1.f - e2) / (1.f + e2);
                const float hold = h[(size_t)b * 512 + d];
                h[(size_t)b * 512 + d] = (1.f - z) * n + z * hold;
            }
        }
        grid_barrier(bar, bar + 1, 64);
    }

    // ======== final: out[:,63] and hT ========
    {
        const int b = blk;
        float p0 = 0.f, p1 = 0.f, p2 = 0.f;
        if (tid < 512) {
            const float hv = h[(size_t)b * 512 + tid];
            p0 = hv * Wo_w[tid * 3 + 0];
            p1 = hv * Wo_w[tid * 3 + 1];
            p2 = hv * Wo_w[tid * 3 + 2];
        }
        #pragma unroll
        for (int off = 32; off > 0; off >>= 1) {
            p0 += __shfl_down(p0, off);
            p1 += __shfl_down(p1, off);
            p2 += __shfl_down(p2, off);
        }
        float* red = smem + 16384;
        if (lane == 0 && wv < 8) { red[wv * 3] = p0; red[wv * 3 + 1] = p1; red[wv * 3 + 2] = p2; }
        __syncthreads();
        if (tid < 3) {
            float s_ = Wo_b[tid];
            for (int w2 = 0; w2 < 8; ++w2) s_ += red[w2 * 3 + tid];
            out[((size_t)b * 64 + 63) * 3 + tid] = s_;
        }
        if (tid < 512) out[12288 + (size_t)b * 512 + tid] = h[(size_t)b * 512 + tid];  // hT
    }
}

extern "C" void kernel_launch(void* const* d_in, const int* in_sizes, int n_in,
                              void* d_out, int out_size, void* d_ws, size_t ws_size,
                              hipStream_t stream) {
    const float* e_all  = (const float*)d_in[0];
    const float* e_last = (const float*)d_in[1];
    const float* Wa_w   = (const float*)d_in[2];
    const float* Wa_b   = (const float*)d_in[3];
    const float* Ua_w   = (const float*)d_in[4];
    const float* Ua_b   = (const float*)d_in[5];
    const float* Va_w   = (const float*)d_in[6];
    const float* Va_b   = (const float*)d_in[7];
    const float* W_ih   = (const float*)d_in[8];
    const float* W_hh   = (const float*)d_in[9];
    const float* b_ih   = (const float*)d_in[10];
    const float* b_hh   = (const float*)d_in[11];
    const float* Wo_w   = (const float*)d_in[12];
    const float* Wo_b   = (const float*)d_in[13];
    float* outp = (float*)d_out;
    float* ws   = (float*)d_ws;

    hipLaunchKernelGGL(prep_kernel, dim3(512), dim3(256), 0, stream,
                       e_all, e_last, Ua_w, Ua_b, W_ih, W_hh, ws);

    void* args[] = { (void*)&e_all, (void*)&Wa_w, (void*)&Wa_b, (void*)&Va_w, (void*)&Va_b,
                     (void*)&b_ih, (void*)&b_hh, (void*)&Wo_w, (void*)&Wo_b,
                     (void*)&outp, (void*)&ws };
    hipError_t err = hipLaunchCooperativeKernel((void*)decode_kernel, dim3(64), dim3(1024),
                                                args, 0, stream);
    if (err != hipSuccess) {
        // fallback: plain launch — 64 blocks x 1024 thr trivially co-resident on 256 CUs,
        // and our barrier does not depend on cooperative-launch kernargs.
        hipLaunchKernelGGL(decode_kernel, dim3(64), dim3(1024), 0, stream,
                           e_all, Wa_w, Wa_b, Va_w, Va_b, b_ih, b_hh, Wo_w, Wo_b, outp, ws);
    }
}

// Round 2
// 6106.878 us; speedup vs baseline: 1.5694x; 1.5694x over previous
//
#include <hip/hip_runtime.h>

// B=64, S=128, D=512, T=64.
// ws float offsets:
#define OFF_UK   0u          // Uk [B*S*D] = 4194304
#define OFF_HBUF 4194304u    // h double buffer 2 x [B*D] = 65536
#define OFF_CTX  4259840u    // ctx [B*D] = 32768
#define OFF_WIH  4292608u    // W_ih ctx-part repacked [1536*512] = 786432
#define OFF_CNT  5079040u    // 128 u32 counters: hc[64], cc[64]
// out float offsets:
#define OFF_OUT_HT  12288u
#define OFF_OUT_ATT 45056u

#define NATTN 64
#define NCB   128
#define NBLK  192
#define NTHR  512
#define DYN_LDS 160000

__device__ __forceinline__ float fast_rcp(float x) { return __builtin_amdgcn_rcpf(x); }
__device__ __forceinline__ float tanh_f(float x) {
    x = fminf(fmaxf(x, -15.f), 15.f);
    float e = __expf(-2.f * x);
    return (1.f - e) * fast_rcp(1.f + e);
}
__device__ __forceinline__ float sigm_f(float x) {
    return fast_rcp(1.f + __expf(-x));
}

__device__ __forceinline__ void wait_cnt(const unsigned* p, unsigned tgt) {
    if (threadIdx.x == 0) {
        while (__hip_atomic_load(p, __ATOMIC_ACQUIRE, __HIP_MEMORY_SCOPE_AGENT) < tgt)
            __builtin_amdgcn_s_sleep(2);
    }
    __syncthreads();
}
__device__ __forceinline__ void signal_cnt(unsigned* p) {
    __syncthreads();   // drains vmcnt for all threads' stores
    if (threadIdx.x == 0) {
        __threadfence();
        __hip_atomic_fetch_add(p, 1u, __ATOMIC_RELEASE, __HIP_MEMORY_SCOPE_AGENT);
    }
}

// ---------------- prep: Uk GEMM + W_ih repack + h0 + counter zero ----------------
__global__ __launch_bounds__(256) void prep_kernel(
    const float* __restrict__ e_all, const float* __restrict__ e_last,
    const float* __restrict__ Ua_w,  const float* __restrict__ Ua_b,
    const float* __restrict__ W_ih,
    float* __restrict__ ws)
{
    float* Uk   = ws + OFF_UK;
    float* h1   = ws + OFF_HBUF + 32768;   // h buffer 1 (read at t=0)
    float* WihP = ws + OFF_WIH;
    unsigned* cnt = (unsigned*)(ws + OFF_CNT);

    __shared__ float a_s[16 * 512];
    const int blk = blockIdx.x, tid = threadIdx.x;

    if (blk == 0 && tid < 128) cnt[tid] = 0u;

    const int r0 = blk * 16;
    for (int i = tid; i < 16 * 512; i += 256) a_s[i] = e_all[(size_t)r0 * 512 + i];
    __syncthreads();

    const int jj = tid & 63, sub = tid >> 6;
    const int rbase = sub * 4 * 512;
    for (int jo = 0; jo < 8; ++jo) {
        const int j = jo * 64 + jj;
        float a0 = 0.f, a1 = 0.f, a2 = 0.f, a3 = 0.f;
        const float* wp = Ua_w + j;
        #pragma unroll 8
        for (int k = 0; k < 512; ++k) {
            const float w = wp[(size_t)k * 512];
            a0 = fmaf(w, a_s[rbase + k],        a0);
            a1 = fmaf(w, a_s[rbase + 512 + k],  a1);
            a2 = fmaf(w, a_s[rbase + 1024 + k], a2);
            a3 = fmaf(w, a_s[rbase + 1536 + k], a3);
        }
        const float bb = Ua_b[j];
        const int r = r0 + sub * 4;
        Uk[(size_t)(r + 0) * 512 + j] = a0 + bb;
        Uk[(size_t)(r + 1) * 512 + j] = a1 + bb;
        Uk[(size_t)(r + 2) * 512 + j] = a2 + bb;
        Uk[(size_t)(r + 3) * 512 + j] = a3 + bb;
    }

    const int gtid = blk * 256 + tid;
    const int gstride = 512 * 256;
    for (int i = gtid; i < 1536 * 512; i += gstride) {
        const int r = i >> 9, k = i & 511;
        WihP[i] = W_ih[(size_t)r * 515 + k];
    }
    for (int i = gtid; i < 64 * 512; i += gstride) h1[i] = e_last[i];
}

// ---------------- persistent decode: 192 blocks x 512 threads ----------------
__global__ __launch_bounds__(512, 1) void decode_kernel(
    const float* __restrict__ e_all,
    const float* __restrict__ Wa_w, const float* __restrict__ Wa_b,
    const float* __restrict__ Va_w,
    const float* __restrict__ W_ih, const float* __restrict__ W_hh,
    const float* __restrict__ b_ih, const float* __restrict__ b_hh,
    const float* __restrict__ Wo_w, const float* __restrict__ Wo_b,
    float* __restrict__ out, float* __restrict__ ws)
{
    extern __shared__ char smraw[];

    float* Uk   = ws + OFF_UK;
    float* hbuf = ws + OFF_HBUF;
    float* ctx  = ws + OFF_CTX;
    const float* WihP = ws + OFF_WIH;
    unsigned* hc = (unsigned*)(ws + OFF_CNT);
    unsigned* cc = hc + 64;

    const int tid = threadIdx.x;
    const int bi  = blockIdx.x;
    const int lane = tid & 63, wv = tid >> 6;

    if (bi < NATTN) {
        // ================= attention block: one per batch element =================
        const int b = bi;
        float* h_s  = (float*)smraw;               // [512]
        float* q_s  = (float*)(smraw + 2048);      // [512]
        float* va_s = (float*)(smraw + 4096);      // [512]
        float* sc_s = (float*)(smraw + 6144);      // [128]
        float* w_s  = (float*)(smraw + 6656);      // [128]
        float* red  = (float*)(smraw + 7168);      // [64]
        float* psq  = (float*)(smraw + 8192);      // [2048]

        if (tid < 512) va_s[tid] = Va_w[tid];

        for (int t = 0; t < 64; ++t) {
            const float* rb = hbuf + ((unsigned)(t + 1) & 1u) * 32768;

            if (t > 0) wait_cnt(&hc[t - 1], 128);
            h_s[tid] = rb[(size_t)b * 512 + tid];
            __syncthreads();

            // ---- q = h @ Wa + Wa_b : k-split-4 partials ----
            {
                const int jq = tid & 127, kc = tid >> 7;
                const float4* wa4 = (const float4*)Wa_w;
                float4 a = {0.f, 0.f, 0.f, 0.f};
                #pragma unroll 8
                for (int it = 0; it < 128; ++it) {
                    const int k = kc * 128 + it;
                    const float hv = h_s[k];
                    const float4 w4 = wa4[(size_t)k * 128 + jq];
                    a.x = fmaf(hv, w4.x, a.x);
                    a.y = fmaf(hv, w4.y, a.y);
                    a.z = fmaf(hv, w4.z, a.z);
                    a.w = fmaf(hv, w4.w, a.w);
                }
                ((float4*)psq)[kc * 128 + jq] = a;
            }
            __syncthreads();
            q_s[tid] = psq[tid] + psq[512 + tid] + psq[1024 + tid] + psq[1536 + tid] + Wa_b[tid];
            __syncthreads();

            // ---- scores: s-groups of 4 per wave, k in registers ----
            {
                const int kl = lane & 15;
                float4 qreg[8], vreg[8];
                const float4* q4 = (const float4*)q_s;
                const float4* v4 = (const float4*)va_s;
                #pragma unroll
                for (int it = 0; it < 8; ++it) { qreg[it] = q4[it * 16 + kl]; vreg[it] = v4[it * 16 + kl]; }
                const int sbase = wv * 16 + (lane >> 4);
                #pragma unroll
                for (int sg = 0; sg < 4; ++sg) {
                    const int s = sbase + sg * 4;
                    const float4* uk4 = (const float4*)(Uk + ((size_t)b * 128 + s) * 512);
                    float acc = 0.f;
                    #pragma unroll
                    for (int it = 0; it < 8; ++it) {
                        const float4 u = uk4[it * 16 + kl];
                        const float4 qv = qreg[it], vv = vreg[it];
                        acc = fmaf(tanh_f(qv.x + u.x), vv.x, acc);
                        acc = fmaf(tanh_f(qv.y + u.y), vv.y, acc);
                        acc = fmaf(tanh_f(qv.z + u.z), vv.z, acc);
                        acc = fmaf(tanh_f(qv.w + u.w), vv.w, acc);
                    }
                    acc += __shfl_xor(acc, 1); acc += __shfl_xor(acc, 2);
                    acc += __shfl_xor(acc, 4); acc += __shfl_xor(acc, 8);
                    if (kl == 0) sc_s[s] = acc;   // Va_b: softmax-invariant shift
                }
            }
            __syncthreads();

            // ---- softmax over 128 ----
            if (tid < 64) {
                float mx = fmaxf(sc_s[tid], sc_s[tid + 64]);
                #pragma unroll
                for (int off = 32; off > 0; off >>= 1) mx = fmaxf(mx, __shfl_down(mx, off));
                if (tid == 0) red[0] = mx;
            }
            __syncthreads();
            if (tid < 128) w_s[tid] = __expf(sc_s[tid] - red[0]);
            __syncthreads();
            if (tid < 64) {
                float sm = w_s[tid] + w_s[tid + 64];
                #pragma unroll
                for (int off = 32; off > 0; off >>= 1) sm += __shfl_down(sm, off);
                if (tid == 0) red[1] = fast_rcp(sm);
            }
            __syncthreads();
            if (tid < 128) {
                const float wn = w_s[tid] * red[1];
                w_s[tid] = wn;
                out[OFF_OUT_ATT + ((size_t)b * 64 + t) * 128 + tid] = wn;
            }
            __syncthreads();

            // ---- ctx = w @ e_all[b], s-split-4 partials ----
            {
                const int dq = tid & 127, sg = tid >> 7;
                const float4* e4 = (const float4*)(e_all + (size_t)b * 128 * 512);
                float4 a = {0.f, 0.f, 0.f, 0.f};
                #pragma unroll 4
                for (int si = 0; si < 32; ++si) {
                    const int s = sg * 32 + si;
                    const float wgt = w_s[s];
                    const float4 ev = e4[(size_t)s * 128 + dq];
                    a.x = fmaf(wgt, ev.x, a.x);
                    a.y = fmaf(wgt, ev.y, a.y);
                    a.z = fmaf(wgt, ev.z, a.z);
                    a.w = fmaf(wgt, ev.w, a.w);
                }
                ((float4*)psq)[sg * 128 + dq] = a;
            }
            __syncthreads();
            if (tid < 128) {
                const float4* p4 = (const float4*)psq;
                float4 a = p4[tid], b2 = p4[128 + tid], c2 = p4[256 + tid], d2 = p4[384 + tid];
                float4 r;
                r.x = a.x + b2.x + c2.x + d2.x;
                r.y = a.y + b2.y + c2.y + d2.y;
                r.z = a.z + b2.z + c2.z + d2.z;
                r.w = a.w + b2.w + c2.w + d2.w;
                ((float4*)(ctx + (size_t)b * 512))[tid] = r;
            }

            // ---- out[b, t-1] = h_{t-1} @ Wo + Wo_b (before releasing ctx) ----
            if (t > 0) {
                const float hv = h_s[tid];
                float p0 = hv * Wo_w[tid * 3 + 0];
                float p1 = hv * Wo_w[tid * 3 + 1];
                float p2 = hv * Wo_w[tid * 3 + 2];
                #pragma unroll
                for (int off = 32; off > 0; off >>= 1) {
                    p0 += __shfl_down(p0, off);
                    p1 += __shfl_down(p1, off);
                    p2 += __shfl_down(p2, off);
                }
                if (lane == 0) { red[8 + wv * 3] = p0; red[8 + wv * 3 + 1] = p1; red[8 + wv * 3 + 2] = p2; }
                __syncthreads();
                if (tid < 3) {
                    float s_ = Wo_b[tid];
                    #pragma unroll
                    for (int w2 = 0; w2 < 8; ++w2) s_ += red[8 + w2 * 3 + tid];
                    out[((size_t)b * 64 + (t - 1)) * 3 + tid] = s_;
                }
            }

            signal_cnt(&cc[t]);
        }

        // ---- final: out[:,63] and hT ----
        wait_cnt(&hc[63], 128);
        const float* rb = hbuf + 32768;   // buffer (63 & 1) == 1
        h_s[tid] = rb[(size_t)b * 512 + tid];
        out[OFF_OUT_HT + (size_t)b * 512 + tid] = h_s[tid];
        __syncthreads();
        {
            const float hv = h_s[tid];
            float p0 = hv * Wo_w[tid * 3 + 0];
            float p1 = hv * Wo_w[tid * 3 + 1];
            float p2 = hv * Wo_w[tid * 3 + 2];
            #pragma unroll
            for (int off = 32; off > 0; off >>= 1) {
                p0 += __shfl_down(p0, off);
                p1 += __shfl_down(p1, off);
                p2 += __shfl_down(p2, off);
            }
            if (lane == 0) { red[8 + wv * 3] = p0; red[8 + wv * 3 + 1] = p1; red[8 + wv * 3 + 2] = p2; }
            __syncthreads();
            if (tid < 3) {
                float s_ = Wo_b[tid];
                #pragma unroll
                for (int w2 = 0; w2 < 8; ++w2) s_ += red[8 + w2 * 3 + tid];
                out[((size_t)b * 64 + 63) * 3 + tid] = s_;
            }
        }
    } else {
        // ================= gate block: owns hidden dims d0..d0+3 =================
        const int cb = bi - NATTN;
        const int d0 = cb * 4;
        float4* hb4 = (float4*)smraw;                     // [64*128] float4 = 131072 B
        float*  ps   = (float*)(smraw + 131072);          // [768*8]
        float*  gh_s = (float*)(smraw + 155648);          // [768]
        float*  x_s  = (float*)(smraw + 158720);          // [192]
        float*  wx_s = (float*)(smraw + 159488);          // [36]

        const int bt = tid >> 5, i5 = (tid >> 3) & 3, ks = tid & 7;
        const int rR = d0 + i5, rZ = 512 + d0 + i5, rN = 1024 + d0 + i5;

        if (tid < 36) {
            const int c = tid / 3, xc = tid - c * 3;
            const int g = c >> 2, ii = c & 3;
            wx_s[tid] = W_ih[(size_t)(g * 512 + d0 + ii) * 515 + 512 + xc];
        }

        for (int t = 0; t < 64; ++t) {
            const float* rb = hbuf + ((unsigned)(t + 1) & 1u) * 32768;
            float*       wb = hbuf + ((unsigned)t & 1u) * 32768;

            if (t > 0) wait_cnt(&hc[t - 1], 128);
            // stage full h into LDS
            {
                const float4* s4 = (const float4*)rb;
                #pragma unroll
                for (int u = 0; u < 16; ++u) hb4[u * 512 + tid] = s4[u * 512 + tid];
            }
            __syncthreads();

            // ---- gh = h @ W_hh^T (12 cols), tile 4b x 3g, k-interleaved ----
            {
                const float4* wg0 = (const float4*)W_hh + (size_t)rR * 128;
                const float4* wg1 = (const float4*)W_hh + (size_t)rZ * 128;
                const float4* wg2 = (const float4*)W_hh + (size_t)rN * 128;
                float acc[12];
                #pragma unroll
                for (int j = 0; j < 12; ++j) acc[j] = 0.f;
                #pragma unroll 4
                for (int it = 0; it < 16; ++it) {
                    const int k4 = it * 8 + ks;
                    const float4 w0 = wg0[k4], w1 = wg1[k4], w2 = wg2[k4];
                    #pragma unroll
                    for (int j = 0; j < 4; ++j) {
                        const float4 hv = hb4[(bt * 4 + j) * 128 + k4];
                        acc[j*3+0] = fmaf(hv.x, w0.x, fmaf(hv.y, w0.y, fmaf(hv.z, w0.z, fmaf(hv.w, w0.w, acc[j*3+0]))));
                        acc[j*3+1] = fmaf(hv.x, w1.x, fmaf(hv.y, w1.y, fmaf(hv.z, w1.z, fmaf(hv.w, w1.w, acc[j*3+1]))));
                        acc[j*3+2] = fmaf(hv.x, w2.x, fmaf(hv.y, w2.y, fmaf(hv.z, w2.z, fmaf(hv.w, w2.w, acc[j*3+2]))));
                    }
                }
                #pragma unroll
                for (int j = 0; j < 4; ++j) {
                    const int ob = (bt * 4 + j) * 12;
                    ps[(ob + i5) * 8 + ks]     = acc[j*3+0];
                    ps[(ob + 4 + i5) * 8 + ks] = acc[j*3+1];
                    ps[(ob + 8 + i5) * 8 + ks] = acc[j*3+2];
                }
            }
            __syncthreads();
            for (int o = tid; o < 768; o += 512) {
                float s = 0.f;
                #pragma unroll
                for (int u = 0; u < 8; ++u) s += ps[o * 8 + u];
                const int bb = o / 12, c = o - bb * 12, g = c >> 2, ii = c & 3;
                gh_s[o] = s + b_hh[g * 512 + d0 + ii];
            }

            wait_cnt(&cc[t], 64);
            // stage full ctx into LDS (reuse hb4) + x vector
            {
                const float4* s4 = (const float4*)ctx;
                #pragma unroll
                for (int u = 0; u < 16; ++u) hb4[u * 512 + tid] = s4[u * 512 + tid];
            }
            if (tid < 192) {
                const int bb = tid / 3, xc = tid - bb * 3;
                x_s[tid] = (t > 0) ? out[((size_t)bb * 64 + (t - 1)) * 3 + xc] : 0.f;
            }
            __syncthreads();

            // ---- gi = ctx @ W_ih^T (ctx part) ----
            {
                const float4* wg0 = (const float4*)WihP + (size_t)rR * 128;
                const float4* wg1 = (const float4*)WihP + (size_t)rZ * 128;
                const float4* wg2 = (const float4*)WihP + (size_t)rN * 128;
                float acc[12];
                #pragma unroll
                for (int j = 0; j < 12; ++j) acc[j] = 0.f;
                #pragma unroll 4
                for (int it = 0; it < 16; ++it) {
                    const int k4 = it * 8 + ks;
                    const float4 w0 = wg0[k4], w1 = wg1[k4], w2 = wg2[k4];
                    #pragma unroll
                    for (int j = 0; j < 4; ++j) {
                        const float4 hv = hb4[(bt * 4 + j) * 128 + k4];
                        acc[j*3+0] = fmaf(hv.x, w0.x, fmaf(hv.y, w0.y, fmaf(hv.z, w0.z, fmaf(hv.w, w0.w, acc[j*3+0]))));
                        acc[j*3+1] = fmaf(hv.x, w1.x, fmaf(hv.y, w1.y, fmaf(hv.z, w1.z, fmaf(hv.w, w1.w, acc[j*3+1]))));
                        acc[j*3+2] = fmaf(hv.x, w2.x, fmaf(hv.y, w2.y, fmaf(hv.z, w2.z, fmaf(hv.w, w2.w, acc[j*3+2]))));
                    }
                }
                #pragma unroll
                for (int j = 0; j < 4; ++j) {
                    const int ob = (bt * 4 + j) * 12;
                    ps[(ob + i5) * 8 + ks]     = acc[j*3+0];
                    ps[(ob + 4 + i5) * 8 + ks] = acc[j*3+1];
                    ps[(ob + 8 + i5) * 8 + ks] = acc[j*3+2];
                }
            }
            __syncthreads();
            for (int o = tid; o < 768; o += 512) {
                float s = 0.f;
                #pragma unroll
                for (int u = 0; u < 8; ++u) s += ps[o * 8 + u];
                const int bb = o / 12, c = o - bb * 12, g = c >> 2, ii = c & 3;
                s += b_ih[g * 512 + d0 + ii];
                s += x_s[bb * 3 + 0] * wx_s[c * 3 + 0]
                   + x_s[bb * 3 + 1] * wx_s[c * 3 + 1]
                   + x_s[bb * 3 + 2] * wx_s[c * 3 + 2];
                ps[o * 8] = s;
            }
            __syncthreads();

            // ---- gates + h update ----
            if (tid < 256) {
                const int bb = tid >> 2, ii = tid & 3, d = d0 + ii;
                const int oR = bb * 12 + ii, oZ = oR + 4, oN = oR + 8;
                const float r = sigm_f(ps[oR * 8] + gh_s[oR]);
                const float z = sigm_f(ps[oZ * 8] + gh_s[oZ]);
                const float n = tanh_f(ps[oN * 8] + r * gh_s[oN]);
                const float hold = rb[(size_t)bb * 512 + d];
                wb[(size_t)bb * 512 + d] = (1.f - z) * n + z * hold;
            }
            signal_cnt(&hc[t]);
        }
    }
}

extern "C" void kernel_launch(void* const* d_in, const int* in_sizes, int n_in,
                              void* d_out, int out_size, void* d_ws, size_t ws_size,
                              hipStream_t stream) {
    const float* e_all  = (const float*)d_in[0];
    const float* e_last = (const float*)d_in[1];
    const float* Wa_w   = (const float*)d_in[2];
    const float* Wa_b   = (const float*)d_in[3];
    const float* Ua_w   = (const float*)d_in[4];
    const float* Ua_b   = (const float*)d_in[5];
    const float* Va_w   = (const float*)d_in[6];
    const float* W_ih   = (const float*)d_in[8];
    const float* W_hh   = (const float*)d_in[9];
    const float* b_ih   = (const float*)d_in[10];
    const float* b_hh   = (const float*)d_in[11];
    const float* Wo_w   = (const float*)d_in[12];
    const float* Wo_b   = (const float*)d_in[13];
    float* outp = (float*)d_out;
    float* ws   = (float*)d_ws;

    static int attr_done = -1;
    hipFuncSetAttribute((const void*)decode_kernel,
                        hipFuncAttributeMaxDynamicSharedMemorySize, DYN_LDS);
    (void)attr_done;

    hipLaunchKernelGGL(prep_kernel, dim3(512), dim3(256), 0, stream,
                       e_all, e_last, Ua_w, Ua_b, W_ih, ws);

    void* args[] = { (void*)&e_all, (void*)&Wa_w, (void*)&Wa_b, (void*)&Va_w,
                     (void*)&W_ih, (void*)&W_hh, (void*)&b_ih, (void*)&b_hh,
                     (void*)&Wo_w, (void*)&Wo_b, (void*)&outp, (void*)&ws };
    hipError_t err = hipLaunchCooperativeKernel((void*)decode_kernel, dim3(NBLK), dim3(NTHR),
                                                args, DYN_LDS, stream);
    if (err != hipSuccess) {
        // 192 blocks x 512 thr @ 1 block/CU trivially co-resident; counters don't
        // depend on cooperative-launch kernargs.
        hipLaunchKernelGGL(decode_kernel, dim3(NBLK), dim3(NTHR), DYN_LDS, stream,
                           e_all, Wa_w, Wa_b, Va_w, W_ih, W_hh, b_ih, b_hh,
                           Wo_w, Wo_b, outp, ws);
    }
}

// Round 4
// 4551.962 us; speedup vs baseline: 2.1055x; 1.3416x over previous
//
#include <hip/hip_runtime.h>

// B=64, S=128, D=512, T=64
// ws float offsets (fp32 exchange everywhere):
#define OFF_UK   0u          // Uk [B*S*D] = 4194304
#define OFF_H    4194304u    // h  [B*D]   = 32768
#define OFF_CTX  4227072u    // ctx[B*D]   = 32768
#define OFF_Q    4259840u    // q col-major q[col*64+b] = 32768
#define OFF_XMIR 4292608u    // 256
#define OFF_CNT  4292864u    // u32[24576]: 3 phases x 64 steps x 8 stripes x 16 u32 (64B apart)
// out float offsets:
#define OFF_OUT_HT  12288u
#define OFF_OUT_ATT 45056u

#define NBLK 192
#define NTHR 512
#define DYN_LDS 139264

// counter base for phase p (0=q,1=ctx,2=h), step t
#define CNT_BASE(cnt, p, t) ((cnt) + (((p) * 64 + (t)) * 8) * 16)

__device__ __forceinline__ float fast_rcp(float x) { return __builtin_amdgcn_rcpf(x); }
__device__ __forceinline__ float tanh_f(float x) {
    x = fminf(fmaxf(x, -15.f), 15.f);
    float e = __expf(-2.f * x);
    return (1.f - e) * fast_rcp(1.f + e);
}
__device__ __forceinline__ float sigm_f(float x) { return fast_rcp(1.f + __expf(-x)); }

// ---- relaxed agent-scope accessors: per-access L1/L2 bypass, NO cache-wide inv/wb ----
template<typename T>
__device__ __forceinline__ T cload(const T* p) {
    return __hip_atomic_load(p, __ATOMIC_RELAXED, __HIP_MEMORY_SCOPE_AGENT);
}
template<typename T>
__device__ __forceinline__ void cstore(T* p, T v) {
    __hip_atomic_store(p, v, __ATOMIC_RELAXED, __HIP_MEMORY_SCOPE_AGENT);
}
__device__ __forceinline__ double pack2f(float a, float b) {
    union { double d; float f[2]; } u; u.f[0] = a; u.f[1] = b; return u.d;
}

// 8 striped counters, 64B apart. Ordering: producer stores complete (vmcnt drained
// at the __syncthreads inside signal8) BEFORE the counter RMW issues; consumer
// polls counter then reads data with cache-bypass loads -> no stale-cache hazard.
__device__ __forceinline__ void wait8(const unsigned* c, unsigned tgt) {
    if (threadIdx.x < 8) {
        const unsigned* p = c + threadIdx.x * 16;
        while (__hip_atomic_load(p, __ATOMIC_RELAXED, __HIP_MEMORY_SCOPE_AGENT) < tgt)
            __builtin_amdgcn_s_sleep(1);
    }
    __syncthreads();
}
__device__ __forceinline__ void signal8(unsigned* c, int stripe) {
    __syncthreads();
    if (threadIdx.x == 0)
        __hip_atomic_fetch_add(c + stripe * 16, 1u, __ATOMIC_RELAXED, __HIP_MEMORY_SCOPE_AGENT);
}

// ---------------- prep: Uk GEMM + h0 + counter zero ----------------
__global__ __launch_bounds__(256) void prep_kernel(
    const float* __restrict__ e_all, const float* __restrict__ e_last,
    const float* __restrict__ Ua_w,  const float* __restrict__ Ua_b,
    float* __restrict__ ws)
{
    float* Uk = ws + OFF_UK;
    float* Hf = ws + OFF_H;
    unsigned* cnt = (unsigned*)(ws + OFF_CNT);

    __shared__ float a_s[16 * 512];
    const int blk = blockIdx.x, tid = threadIdx.x;

    const int gtid = blk * 256 + tid, gstride = 512 * 256;
    for (int i = gtid; i < 24576; i += gstride) cnt[i] = 0u;

    const int r0 = blk * 16;
    for (int i = tid; i < 16 * 512; i += 256) a_s[i] = e_all[(size_t)r0 * 512 + i];
    __syncthreads();

    const int jj = tid & 63, sub = tid >> 6;
    const int rbase = sub * 4 * 512;
    for (int jo = 0; jo < 8; ++jo) {
        const int j = jo * 64 + jj;
        float a0 = 0.f, a1 = 0.f, a2 = 0.f, a3 = 0.f;
        const float* wp = Ua_w + j;
        #pragma unroll 8
        for (int k = 0; k < 512; ++k) {
            const float w = wp[(size_t)k * 512];
            a0 = fmaf(w, a_s[rbase + k],        a0);
            a1 = fmaf(w, a_s[rbase + 512 + k],  a1);
            a2 = fmaf(w, a_s[rbase + 1024 + k], a2);
            a3 = fmaf(w, a_s[rbase + 1536 + k], a3);
        }
        const float bb = Ua_b[j];
        const int r = r0 + sub * 4;
        Uk[(size_t)(r + 0) * 512 + j] = a0 + bb;
        Uk[(size_t)(r + 1) * 512 + j] = a1 + bb;
        Uk[(size_t)(r + 2) * 512 + j] = a2 + bb;
        Uk[(size_t)(r + 3) * 512 + j] = a3 + bb;
    }

    for (int i = gtid; i < 32768; i += gstride) Hf[i] = e_last[i];
}

// ---------------- persistent decode: 64 attn + 128 gate blocks ----------------
__global__ __launch_bounds__(512, 1) void decode_kernel(
    const float* __restrict__ e_all,  const float* __restrict__ e_last,
    const float* __restrict__ Wa_w,   const float* __restrict__ Wa_b,
    const float* __restrict__ Va_w,
    const float* __restrict__ W_ih,   const float* __restrict__ W_hh,
    const float* __restrict__ b_ih,   const float* __restrict__ b_hh,
    const float* __restrict__ Wo_w,   const float* __restrict__ Wo_b,
    float* __restrict__ out, float* __restrict__ ws)
{
    extern __shared__ char smraw[];

    float* Uk = ws + OFF_UK;
    float* Hf = ws + OFF_H;
    float* Cf = ws + OFF_CTX;
    float* qg   = ws + OFF_Q;
    float* xmir = ws + OFF_XMIR;
    unsigned* cnt = (unsigned*)(ws + OFF_CNT);

    const int tid = threadIdx.x;
    const int bi  = blockIdx.x;
    const int lane = tid & 63, wv = tid >> 6;

    if (bi < 64) {
        // ===================== attention block (one per b) =====================
        const int b = bi;
        float* h_s  = (float*)smraw;               // 512
        float* q_s  = (float*)(smraw + 2048);      // 512
        float* va_s = (float*)(smraw + 4096);      // 512
        float* sc_s = (float*)(smraw + 6144);      // 128
        float* w_s  = (float*)(smraw + 6656);      // 128
        float* red  = (float*)(smraw + 7168);      // 64
        float* psq  = (float*)(smraw + 7424);      // 2048

        va_s[tid] = Va_w[tid];

        for (int t = 0; t < 64; ++t) {
            wait8(CNT_BASE(cnt, 0, t), 16);      // all gate blocks wrote q_t (implies h_t stable)

            h_s[tid] = cload(Hf + (size_t)b * 512 + tid);
            q_s[tid] = cload(qg + (size_t)tid * 64 + b);
            __syncthreads();

            // ---- scores ----
            {
                const int kl = lane & 15;
                float4 qreg[8], vreg[8];
                const float4* q4 = (const float4*)q_s;
                const float4* v4 = (const float4*)va_s;
                #pragma unroll
                for (int it = 0; it < 8; ++it) { qreg[it] = q4[it * 16 + kl]; vreg[it] = v4[it * 16 + kl]; }
                const int sbase = wv * 16 + (lane >> 4);
                #pragma unroll
                for (int sg = 0; sg < 4; ++sg) {
                    const int s = sbase + sg * 4;
                    const float4* uk4 = (const float4*)(Uk + ((size_t)b * 128 + s) * 512);
                    float acc = 0.f;
                    #pragma unroll
                    for (int it = 0; it < 8; ++it) {
                        const float4 u = uk4[it * 16 + kl];
                        const float4 qv = qreg[it], vv = vreg[it];
                        acc = fmaf(tanh_f(qv.x + u.x), vv.x, acc);
                        acc = fmaf(tanh_f(qv.y + u.y), vv.y, acc);
                        acc = fmaf(tanh_f(qv.z + u.z), vv.z, acc);
                        acc = fmaf(tanh_f(qv.w + u.w), vv.w, acc);
                    }
                    acc += __shfl_xor(acc, 1); acc += __shfl_xor(acc, 2);
                    acc += __shfl_xor(acc, 4); acc += __shfl_xor(acc, 8);
                    if (kl == 0) sc_s[s] = acc;   // Va_b: softmax-invariant shift
                }
            }
            __syncthreads();

            // ---- softmax over 128 ----
            if (tid < 64) {
                float mx = fmaxf(sc_s[tid], sc_s[tid + 64]);
                #pragma unroll
                for (int off = 32; off > 0; off >>= 1) mx = fmaxf(mx, __shfl_down(mx, off));
                if (tid == 0) red[0] = mx;
            }
            __syncthreads();
            if (tid < 128) w_s[tid] = __expf(sc_s[tid] - red[0]);
            __syncthreads();
            if (tid < 64) {
                float sm = w_s[tid] + w_s[tid + 64];
                #pragma unroll
                for (int off = 32; off > 0; off >>= 1) sm += __shfl_down(sm, off);
                if (tid == 0) red[1] = fast_rcp(sm);
            }
            __syncthreads();
            if (tid < 128) {
                const float wn = w_s[tid] * red[1];
                w_s[tid] = wn;
                out[OFF_OUT_ATT + ((size_t)b * 64 + t) * 128 + tid] = wn;
            }
            __syncthreads();

            // ---- ctx = w @ e_all[b] (s-split-4 partials) ----
            {
                const int dq = tid & 127, sg = tid >> 7;
                const float4* e4 = (const float4*)(e_all + (size_t)b * 128 * 512);
                float4 a = {0.f, 0.f, 0.f, 0.f};
                #pragma unroll 4
                for (int si = 0; si < 32; ++si) {
                    const int s = sg * 32 + si;
                    const float wgt = w_s[s];
                    const float4 ev = e4[(size_t)s * 128 + dq];
                    a.x = fmaf(wgt, ev.x, a.x);
                    a.y = fmaf(wgt, ev.y, a.y);
                    a.z = fmaf(wgt, ev.z, a.z);
                    a.w = fmaf(wgt, ev.w, a.w);
                }
                ((float4*)psq)[sg * 128 + dq] = a;
            }
            __syncthreads();
            if (tid < 128) {
                const float4* p4 = (const float4*)psq;
                float4 a = p4[tid], b2 = p4[128 + tid], c2 = p4[256 + tid], d2 = p4[384 + tid];
                float4 r;
                r.x = a.x + b2.x + c2.x + d2.x;
                r.y = a.y + b2.y + c2.y + d2.y;
                r.z = a.z + b2.z + c2.z + d2.z;
                r.w = a.w + b2.w + c2.w + d2.w;
                double* cd = (double*)(Cf + (size_t)b * 512);
                cstore(cd + tid * 2,     pack2f(r.x, r.y));
                cstore(cd + tid * 2 + 1, pack2f(r.z, r.w));
            }

            // ---- out coords for step t-1 (uses h_t = h_s) + mirror for gates ----
            if (t > 0) {
                const float hv = h_s[tid];
                float p0 = hv * Wo_w[tid * 3 + 0];
                float p1 = hv * Wo_w[tid * 3 + 1];
                float p2 = hv * Wo_w[tid * 3 + 2];
                #pragma unroll
                for (int off = 32; off > 0; off >>= 1) {
                    p0 += __shfl_down(p0, off);
                    p1 += __shfl_down(p1, off);
                    p2 += __shfl_down(p2, off);
                }
                if (lane == 0) { red[8 + wv * 3] = p0; red[8 + wv * 3 + 1] = p1; red[8 + wv * 3 + 2] = p2; }
                __syncthreads();
                if (tid < 3) {
                    float s_ = Wo_b[tid];
                    #pragma unroll
                    for (int w2 = 0; w2 < 8; ++w2) s_ += red[8 + w2 * 3 + tid];
                    out[((size_t)b * 64 + (t - 1)) * 3 + tid] = s_;
                    cstore(xmir + b * 3 + tid, s_);
                }
            }

            signal8(CNT_BASE(cnt, 1, t), b & 7);
        }

        // ---- final coords t=63 (needs h_64) ----
        wait8(CNT_BASE(cnt, 2, 63), 16);
        h_s[tid] = cload(Hf + (size_t)b * 512 + tid);
        __syncthreads();
        {
            const float hv = h_s[tid];
            float p0 = hv * Wo_w[tid * 3 + 0];
            float p1 = hv * Wo_w[tid * 3 + 1];
            float p2 = hv * Wo_w[tid * 3 + 2];
            #pragma unroll
            for (int off = 32; off > 0; off >>= 1) {
                p0 += __shfl_down(p0, off);
                p1 += __shfl_down(p1, off);
                p2 += __shfl_down(p2, off);
            }
            if (lane == 0) { red[8 + wv * 3] = p0; red[8 + wv * 3 + 1] = p1; red[8 + wv * 3 + 2] = p2; }
            __syncthreads();
            if (tid < 3) {
                float s_ = Wo_b[tid];
                #pragma unroll
                for (int w2 = 0; w2 < 8; ++w2) s_ += red[8 + w2 * 3 + tid];
                out[((size_t)b * 64 + 63) * 3 + tid] = s_;
            }
        }
    } else {
        // ========== gate block: owns dims d0..d0+3 for ALL b, weights in VGPRs ==========
        const int cb = bi - 64, d0 = cb * 4;
        float* hb_s = (float*)smraw;                // 64x512 fp32 = 131072 B (h, then ctx)
        float* gh_s = (float*)(smraw + 131072);     // 768
        float* gi_s = (float*)(smraw + 134144);     // 768
        float* x_s  = (float*)(smraw + 137216);     // 192
        float* wx_s = (float*)(smraw + 137984);     // 36
        float4* hb4 = (float4*)hb_s;

        const int ks = tid & 31, i5 = (tid >> 5) & 3, bt = tid >> 7;
        const int col = d0 + i5;

        // ---- pin weight slices in registers (loaded once, normal cached loads) ----
        float4 wq[4], wh[3][4], wi[3][4];
        #pragma unroll
        for (int i = 0; i < 4; ++i) {
            const int kb = ks * 4 + 128 * i;
            wq[i].x = Wa_w[(size_t)(kb + 0) * 512 + col];
            wq[i].y = Wa_w[(size_t)(kb + 1) * 512 + col];
            wq[i].z = Wa_w[(size_t)(kb + 2) * 512 + col];
            wq[i].w = Wa_w[(size_t)(kb + 3) * 512 + col];
            #pragma unroll
            for (int g = 0; g < 3; ++g) {
                const int r = g * 512 + d0 + i5;
                wh[g][i] = *(const float4*)(W_hh + (size_t)r * 512 + kb);
                const float* wir = W_ih + (size_t)r * 515 + kb;
                wi[g][i] = make_float4(wir[0], wir[1], wir[2], wir[3]);
            }
        }
        const float qbias = Wa_b[col];
        float bhh[3], bih3[3];
        #pragma unroll
        for (int g = 0; g < 3; ++g) bhh[g] = b_hh[g * 512 + d0 + i5];
        if (tid < 36) {
            const int ii = tid / 9, rem = tid - ii * 9, g = rem / 3, c = rem - g * 3;
            wx_s[tid] = W_ih[(size_t)(g * 512 + d0 + ii) * 515 + 512 + c];
        }
        const int bb = tid >> 2, ii = tid & 3;      // gate-update mapping (tid<256)
        float hold = 0.f;
        if (tid < 256) {
            hold = e_last[(size_t)bb * 512 + d0 + ii];
            #pragma unroll
            for (int g = 0; g < 3; ++g) bih3[g] = b_ih[g * 512 + d0 + ii];
        }

        for (int t = 0; t < 64; ++t) {
            if (t > 0) wait8(CNT_BASE(cnt, 2, t - 1), 16);   // h_t ready
            // ---- stage full h_t into LDS (bypass loads) ----
            #pragma unroll 8
            for (int r = 0; r < 64; ++r)
                hb_s[r * 512 + tid] = cload(Hf + (size_t)r * 512 + tid);
            __syncthreads();

            // ---- q = h @ Wa (this block's 4 cols) ----
            {
                float accq[16];
                #pragma unroll
                for (int j = 0; j < 16; ++j) accq[j] = 0.f;
                #pragma unroll
                for (int i = 0; i < 4; ++i) {
                    const float4 w = wq[i];
                    #pragma unroll
                    for (int j = 0; j < 16; ++j) {
                        const float4 hv = hb4[(bt * 16 + j) * 128 + ks + 32 * i];
                        accq[j] = fmaf(hv.x, w.x, fmaf(hv.y, w.y, fmaf(hv.z, w.z, fmaf(hv.w, w.w, accq[j]))));
                    }
                }
                #pragma unroll
                for (int off = 1; off < 32; off <<= 1) {
                    #pragma unroll
                    for (int j = 0; j < 16; ++j) accq[j] += __shfl_xor(accq[j], off);
                }
                if (ks == 0) {
                    double* qd = (double*)(qg + (size_t)col * 64 + bt * 16);
                    #pragma unroll
                    for (int jp = 0; jp < 8; ++jp)
                        cstore(qd + jp, pack2f(accq[2 * jp] + qbias, accq[2 * jp + 1] + qbias));
                }
            }
            signal8(CNT_BASE(cnt, 0, t), cb & 7);

            // ---- gh = h @ W_hh^T ----
            {
                float aR[16], aZ[16], aN[16];
                #pragma unroll
                for (int j = 0; j < 16; ++j) { aR[j] = 0.f; aZ[j] = 0.f; aN[j] = 0.f; }
                #pragma unroll
                for (int i = 0; i < 4; ++i) {
                    const float4 w0 = wh[0][i], w1 = wh[1][i], w2 = wh[2][i];
                    #pragma unroll
                    for (int j = 0; j < 16; ++j) {
                        const float4 hv = hb4[(bt * 16 + j) * 128 + ks + 32 * i];
                        aR[j] = fmaf(hv.x, w0.x, fmaf(hv.y, w0.y, fmaf(hv.z, w0.z, fmaf(hv.w, w0.w, aR[j]))));
                        aZ[j] = fmaf(hv.x, w1.x, fmaf(hv.y, w1.y, fmaf(hv.z, w1.z, fmaf(hv.w, w1.w, aZ[j]))));
                        aN[j] = fmaf(hv.x, w2.x, fmaf(hv.y, w2.y, fmaf(hv.z, w2.z, fmaf(hv.w, w2.w, aN[j]))));
                    }
                }
                #pragma unroll
                for (int off = 1; off < 32; off <<= 1) {
                    #pragma unroll
                    for (int j = 0; j < 16; ++j) {
                        aR[j] += __shfl_xor(aR[j], off);
                        aZ[j] += __shfl_xor(aZ[j], off);
                        aN[j] += __shfl_xor(aN[j], off);
                    }
                }
                if (ks == 0) {
                    #pragma unroll
                    for (int j = 0; j < 16; ++j) {
                        const int ob = (bt * 16 + j) * 12 + i5 * 3;
                        gh_s[ob + 0] = aR[j] + bhh[0];
                        gh_s[ob + 1] = aZ[j] + bhh[1];
                        gh_s[ob + 2] = aN[j] + bhh[2];
                    }
                }
            }

            wait8(CNT_BASE(cnt, 1, t), 8);   // ctx_t + x_{t-1} ready (barrier also guards hb_s reuse)
            // ---- stage full ctx into LDS (reuse hb_s) + x ----
            #pragma unroll 8
            for (int r = 0; r < 64; ++r)
                hb_s[r * 512 + tid] = cload(Cf + (size_t)r * 512 + tid);
            if (tid < 192) x_s[tid] = (t > 0) ? cload(xmir + tid) : 0.f;
            __syncthreads();

            // ---- gi = ctx @ W_ih^T (ctx part) ----
            {
                float aR[16], aZ[16], aN[16];
                #pragma unroll
                for (int j = 0; j < 16; ++j) { aR[j] = 0.f; aZ[j] = 0.f; aN[j] = 0.f; }
                #pragma unroll
                for (int i = 0; i < 4; ++i) {
                    const float4 w0 = wi[0][i], w1 = wi[1][i], w2 = wi[2][i];
                    #pragma unroll
                    for (int j = 0; j < 16; ++j) {
                        const float4 hv = hb4[(bt * 16 + j) * 128 + ks + 32 * i];
                        aR[j] = fmaf(hv.x, w0.x, fmaf(hv.y, w0.y, fmaf(hv.z, w0.z, fmaf(hv.w, w0.w, aR[j]))));
                        aZ[j] = fmaf(hv.x, w1.x, fmaf(hv.y, w1.y, fmaf(hv.z, w1.z, fmaf(hv.w, w1.w, aZ[j]))));
                        aN[j] = fmaf(hv.x, w2.x, fmaf(hv.y, w2.y, fmaf(hv.z, w2.z, fmaf(hv.w, w2.w, aN[j]))));
                    }
                }
                #pragma unroll
                for (int off = 1; off < 32; off <<= 1) {
                    #pragma unroll
                    for (int j = 0; j < 16; ++j) {
                        aR[j] += __shfl_xor(aR[j], off);
                        aZ[j] += __shfl_xor(aZ[j], off);
                        aN[j] += __shfl_xor(aN[j], off);
                    }
                }
                if (ks == 0) {
                    #pragma unroll
                    for (int j = 0; j < 16; ++j) {
                        const int ob = (bt * 16 + j) * 12 + i5 * 3;
                        gi_s[ob + 0] = aR[j];
                        gi_s[ob + 1] = aZ[j];
                        gi_s[ob + 2] = aN[j];
                    }
                }
            }
            __syncthreads();

            // ---- gates + h update ----
            if (tid < 256) {
                const int ob = bb * 12 + ii * 3;
                const float x0 = x_s[bb * 3 + 0], x1 = x_s[bb * 3 + 1], x2 = x_s[bb * 3 + 2];
                float giR = gi_s[ob + 0] + bih3[0]
                          + x0 * wx_s[ii * 9 + 0] + x1 * wx_s[ii * 9 + 1] + x2 * wx_s[ii * 9 + 2];
                float giZ = gi_s[ob + 1] + bih3[1]
                          + x0 * wx_s[ii * 9 + 3] + x1 * wx_s[ii * 9 + 4] + x2 * wx_s[ii * 9 + 5];
                float giN = gi_s[ob + 2] + bih3[2]
                          + x0 * wx_s[ii * 9 + 6] + x1 * wx_s[ii * 9 + 7] + x2 * wx_s[ii * 9 + 8];
                const float r = sigm_f(giR + gh_s[ob + 0]);
                const float z = sigm_f(giZ + gh_s[ob + 1]);
                const float n = tanh_f(giN + r * gh_s[ob + 2]);
                const float hnew = (1.f - z) * n + z * hold;
                hold = hnew;
                cstore(Hf + (size_t)bb * 512 + d0 + ii, hnew);
                if (t == 63)
                    out[OFF_OUT_HT + (size_t)bb * 512 + d0 + ii] = hnew;
            }
            signal8(CNT_BASE(cnt, 2, t), cb & 7);
        }
    }
}

extern "C" void kernel_launch(void* const* d_in, const int* in_sizes, int n_in,
                              void* d_out, int out_size, void* d_ws, size_t ws_size,
                              hipStream_t stream) {
    const float* e_all  = (const float*)d_in[0];
    const float* e_last = (const float*)d_in[1];
    const float* Wa_w   = (const float*)d_in[2];
    const float* Wa_b   = (const float*)d_in[3];
    const float* Ua_w   = (const float*)d_in[4];
    const float* Ua_b   = (const float*)d_in[5];
    const float* Va_w   = (const float*)d_in[6];
    const float* W_ih   = (const float*)d_in[8];
    const float* W_hh   = (const float*)d_in[9];
    const float* b_ih   = (const float*)d_in[10];
    const float* b_hh   = (const float*)d_in[11];
    const float* Wo_w   = (const float*)d_in[12];
    const float* Wo_b   = (const float*)d_in[13];
    float* outp = (float*)d_out;
    float* ws   = (float*)d_ws;

    hipFuncSetAttribute((const void*)decode_kernel,
                        hipFuncAttributeMaxDynamicSharedMemorySize, DYN_LDS);

    hipLaunchKernelGGL(prep_kernel, dim3(512), dim3(256), 0, stream,
                       e_all, e_last, Ua_w, Ua_b, ws);

    void* args[] = { (void*)&e_all, (void*)&e_last, (void*)&Wa_w, (void*)&Wa_b, (void*)&Va_w,
                     (void*)&W_ih, (void*)&W_hh, (void*)&b_ih, (void*)&b_hh,
                     (void*)&Wo_w, (void*)&Wo_b, (void*)&outp, (void*)&ws };
    hipError_t err = hipLaunchCooperativeKernel((void*)decode_kernel, dim3(NBLK), dim3(NTHR),
                                                args, DYN_LDS, stream);
    if (err != hipSuccess) {
        // fallback: 192 blocks x 139KB LDS -> 1 block/CU, all co-resident on 256 CUs
        hipLaunchKernelGGL(decode_kernel, dim3(NBLK), dim3(NTHR), DYN_LDS, stream,
                           e_all, e_last, Wa_w, Wa_b, Va_w, W_ih, W_hh, b_ih, b_hh,
                           Wo_w, Wo_b, outp, ws);
    }
}

// Round 5
// 2660.353 us; speedup vs baseline: 3.6026x; 1.7110x over previous
//
#include <hip/hip_runtime.h>

typedef unsigned int u32;
typedef unsigned long long u64;

// B=64, S=128, D=512, T=64.  4 groups x 16 batches.
// ws byte offsets:
#define OFF_UKB 0u          // u32[64*128*256]  bf16-packed Uk (pairs along d)
#define OFF_ECB 8388608u    // u32[64*128*256]  bf16-packed e_all
#define OFF_EX  16777216u   // tagged exchange, u64 units per group:
//   Hx[2][16*256] | Cx[2][16*256] | Qx[2][16*512] | Xx[2][64]
#define HX_SLOT 4096
#define CX_SLOT 4096
#define QX_SLOT 8192
#define XX_SLOT 64
#define G_U64   32896       // 8192+8192+16384+128
// out float offsets:
#define OFF_OUT_HT  12288u
#define OFF_OUT_ATT 45056u

#define NBLK 192
#define NTHR 512
#define DYN_LDS 98304       // forces 1 block/CU (2x98304 > 160KB)

__device__ __forceinline__ float fast_rcp(float x) { return __builtin_amdgcn_rcpf(x); }
__device__ __forceinline__ float tanh_f(float x) {
    x = fminf(fmaxf(x, -15.f), 15.f);
    float e = __expf(-2.f * x);
    return (1.f - e) * fast_rcp(1.f + e);
}
__device__ __forceinline__ float sigm_f(float x) { return fast_rcp(1.f + __expf(-x)); }

__device__ __forceinline__ u32 packbf2(float a, float b) {
    u32 ua = __float_as_uint(a); ua += 0x7FFFu + ((ua >> 16) & 1u);
    u32 ub = __float_as_uint(b); ub += 0x7FFFu + ((ub >> 16) & 1u);
    return (ua >> 16) | (ub & 0xFFFF0000u);
}
__device__ __forceinline__ float2 unpackbf2(u32 u) {
    return make_float2(__uint_as_float(u << 16), __uint_as_float(u & 0xFFFF0000u));
}

// relaxed agent-scope (IF-coherent) 8B accessors — no cache-wide inv/wb
__device__ __forceinline__ u64 cload64(const u64* p) {
    return __hip_atomic_load(p, __ATOMIC_RELAXED, __HIP_MEMORY_SCOPE_AGENT);
}
__device__ __forceinline__ void cstore64(u64* p, u64 v) {
    __hip_atomic_store(p, v, __ATOMIC_RELAXED, __HIP_MEMORY_SCOPE_AGENT);
}
__device__ __forceinline__ u64 poll_tag(const u64* p, u32 tag) {
    u64 v = cload64(p);
    while ((u32)(v >> 32) != tag) { __builtin_amdgcn_s_sleep(1); v = cload64(p); }
    return v;
}

// ---------------- prep: Uk GEMM (bf16 out) + e_all bf16 pack + H0 tagged ----------------
__global__ __launch_bounds__(256) void prep_kernel(
    const float* __restrict__ e_all, const float* __restrict__ e_last,
    const float* __restrict__ Ua_w,  const float* __restrict__ Ua_b,
    float* __restrict__ ws)
{
    u32* UKB = (u32*)((char*)ws + OFF_UKB);
    u32* ECB = (u32*)((char*)ws + OFF_ECB);
    u64* EX  = (u64*)((char*)ws + OFF_EX);

    __shared__ float a_s[16 * 512];
    const int blk = blockIdx.x, tid = threadIdx.x;
    const int gtid = blk * 256 + tid, gstride = 512 * 256;

    const int r0 = blk * 16;
    for (int i = tid; i < 16 * 512; i += 256) a_s[i] = e_all[(size_t)r0 * 512 + i];
    __syncthreads();

    const int jj = tid & 63, sub = tid >> 6;
    const int rbase = sub * 4 * 512;
    for (int jo = 0; jo < 4; ++jo) {
        const int j0 = (jo * 64 + jj) * 2;
        float a0[4], a1[4];
        #pragma unroll
        for (int r = 0; r < 4; ++r) { a0[r] = 0.f; a1[r] = 0.f; }
        const float* wp = Ua_w + j0;
        #pragma unroll 4
        for (int k = 0; k < 512; ++k) {
            const float w0 = wp[(size_t)k * 512];
            const float w1 = wp[(size_t)k * 512 + 1];
            #pragma unroll
            for (int r = 0; r < 4; ++r) {
                const float hv = a_s[rbase + r * 512 + k];
                a0[r] = fmaf(w0, hv, a0[r]);
                a1[r] = fmaf(w1, hv, a1[r]);
            }
        }
        const float bb0 = Ua_b[j0], bb1 = Ua_b[j0 + 1];
        #pragma unroll
        for (int r = 0; r < 4; ++r) {
            const int row = r0 + sub * 4 + r;
            UKB[(size_t)row * 256 + (j0 >> 1)] = packbf2(a0[r] + bb0, a1[r] + bb1);
        }
    }

    // e_all bf16 pack
    for (int i = gtid; i < 2097152; i += gstride)
        ECB[i] = packbf2(e_all[2 * i], e_all[2 * i + 1]);

    // H0 tagged (tag = 0, slot 0)
    for (int i = gtid; i < 16384; i += gstride) {
        const int g = i >> 12, rem = i & 4095, bl = rem >> 8, d2 = rem & 255;
        u64* Hx = EX + (size_t)g * G_U64;
        const float* ep = e_last + ((size_t)(g * 16 + bl) * 512) + 2 * d2;
        Hx[bl * 256 + d2] = (u64)packbf2(ep[0], ep[1]);
    }
}

// ---------------- persistent decode: per group 16 attn + 32 GRU blocks ----------------
__global__ __launch_bounds__(512, 1) void decode_kernel(
    const float* __restrict__ e_last,
    const float* __restrict__ Wa_w, const float* __restrict__ Wa_b,
    const float* __restrict__ Va_w,
    const float* __restrict__ W_ih, const float* __restrict__ W_hh,
    const float* __restrict__ b_ih, const float* __restrict__ b_hh,
    const float* __restrict__ Wo_w, const float* __restrict__ Wo_b,
    float* __restrict__ out, float* __restrict__ ws)
{
    extern __shared__ char smraw[];

    const u32* UKB = (const u32*)((char*)ws + OFF_UKB);
    const u32* ECB = (const u32*)((char*)ws + OFF_ECB);
    u64* EX = (u64*)((char*)ws + OFF_EX);

    const int tid = threadIdx.x;
    const int bi  = blockIdx.x;
    const int g   = bi / 48, r = bi % 48;
    const int lane = tid & 63, wv = tid >> 6;

    u64* Hx = EX + (size_t)g * G_U64;
    u64* Cx = Hx + 2 * HX_SLOT;
    u64* Qx = Cx + 2 * CX_SLOT;
    u64* Xx = Qx + 2 * QX_SLOT;

    if (r < 16) {
        // ===================== attention block: one per b =====================
        const int bl = r, b = g * 16 + r;
        float* h_s  = (float*)smraw;               // 512
        float* q_s  = (float*)(smraw + 2048);      // 512
        float* va_s = (float*)(smraw + 4096);      // 512
        float* sc_s = (float*)(smraw + 6144);      // 128
        float* w_s  = (float*)(smraw + 6656);      // 128
        float* red  = (float*)(smraw + 7168);      // 64
        float* psq  = (float*)(smraw + 7424);      // 2048 floats

        va_s[tid] = Va_w[tid];

        for (int t = 0; t < 64; ++t) {
            const u32 tagv = (u32)t;
            const int slot = t & 1;
            u64* HxS = Hx + slot * HX_SLOT;
            u64* CxS = Cx + slot * CX_SLOT;
            u64* QxS = Qx + slot * QX_SLOT;
            u64* XxS = Xx + slot * XX_SLOT;

            // poll q (all threads) + h row (tid<256); tags self-validate
            {
                u64 vq = poll_tag(QxS + (size_t)bl * 512 + tid, tagv);
                q_s[tid] = __uint_as_float((u32)vq);
                if (tid < 256) {
                    u64 vh = poll_tag(HxS + (size_t)bl * 256 + tid, tagv);
                    ((float2*)h_s)[tid] = unpackbf2((u32)vh);
                }
            }
            __syncthreads();

            // ---- coords for step t-1 (uses H_t) FIRST, releases x early ----
            if (t > 0) {
                const float hv = h_s[tid];
                float p0 = hv * Wo_w[tid * 3 + 0];
                float p1 = hv * Wo_w[tid * 3 + 1];
                float p2 = hv * Wo_w[tid * 3 + 2];
                #pragma unroll
                for (int off = 32; off > 0; off >>= 1) {
                    p0 += __shfl_down(p0, off);
                    p1 += __shfl_down(p1, off);
                    p2 += __shfl_down(p2, off);
                }
                if (lane == 0) { red[8 + wv * 3] = p0; red[8 + wv * 3 + 1] = p1; red[8 + wv * 3 + 2] = p2; }
                __syncthreads();
                if (tid < 3) {
                    float s_ = Wo_b[tid];
                    #pragma unroll
                    for (int w2 = 0; w2 < 8; ++w2) s_ += red[8 + w2 * 3 + tid];
                    out[((size_t)b * 64 + (t - 1)) * 3 + tid] = s_;
                    cstore64(XxS + bl * 4 + tid, ((u64)tagv << 32) | (u64)__float_as_uint(s_));
                }
                __syncthreads();
            }

            // ---- scores: tanh(q + Uk) . Va   (Uk bf16) ----
            {
                const int kl = lane & 15;
                float4 qa[4], qb[4], vaa[4], vab[4];
                const float4* q4 = (const float4*)q_s;
                const float4* v4 = (const float4*)va_s;
                #pragma unroll
                for (int it = 0; it < 4; ++it) {
                    qa[it] = q4[(it * 16 + kl) * 2];     qb[it] = q4[(it * 16 + kl) * 2 + 1];
                    vaa[it] = v4[(it * 16 + kl) * 2];    vab[it] = v4[(it * 16 + kl) * 2 + 1];
                }
                const int sbase = wv * 16 + (lane >> 4);
                #pragma unroll
                for (int sg = 0; sg < 4; ++sg) {
                    const int s = sbase + sg * 4;
                    const uint4* uk4 = (const uint4*)(UKB + ((size_t)b * 128 + s) * 256);
                    float acc = 0.f;
                    #pragma unroll
                    for (int it = 0; it < 4; ++it) {
                        const uint4 u = uk4[it * 16 + kl];
                        const float2 u0 = unpackbf2(u.x), u1 = unpackbf2(u.y);
                        const float2 u2 = unpackbf2(u.z), u3 = unpackbf2(u.w);
                        acc = fmaf(tanh_f(qa[it].x + u0.x), vaa[it].x, acc);
                        acc = fmaf(tanh_f(qa[it].y + u0.y), vaa[it].y, acc);
                        acc = fmaf(tanh_f(qa[it].z + u1.x), vaa[it].z, acc);
                        acc = fmaf(tanh_f(qa[it].w + u1.y), vaa[it].w, acc);
                        acc = fmaf(tanh_f(qb[it].x + u2.x), vab[it].x, acc);
                        acc = fmaf(tanh_f(qb[it].y + u2.y), vab[it].y, acc);
                        acc = fmaf(tanh_f(qb[it].z + u3.x), vab[it].z, acc);
                        acc = fmaf(tanh_f(qb[it].w + u3.y), vab[it].w, acc);
                    }
                    acc += __shfl_xor(acc, 1); acc += __shfl_xor(acc, 2);
                    acc += __shfl_xor(acc, 4); acc += __shfl_xor(acc, 8);
                    if (kl == 0) sc_s[s] = acc;   // Va_b: softmax-invariant
                }
            }
            __syncthreads();

            // ---- softmax over 128 ----
            if (tid < 64) {
                float mx = fmaxf(sc_s[tid], sc_s[tid + 64]);
                #pragma unroll
                for (int off = 32; off > 0; off >>= 1) mx = fmaxf(mx, __shfl_down(mx, off));
                if (tid == 0) red[0] = mx;
            }
            __syncthreads();
            if (tid < 128) w_s[tid] = __expf(sc_s[tid] - red[0]);
            __syncthreads();
            if (tid < 64) {
                float sm = w_s[tid] + w_s[tid + 64];
                #pragma unroll
                for (int off = 32; off > 0; off >>= 1) sm += __shfl_down(sm, off);
                if (tid == 0) red[1] = fast_rcp(sm);
            }
            __syncthreads();
            if (tid < 128) {
                const float wn = w_s[tid] * red[1];
                w_s[tid] = wn;
                out[OFF_OUT_ATT + ((size_t)b * 64 + t) * 128 + tid] = wn;
            }
            __syncthreads();

            // ---- ctx = w @ e_all[b]  (e bf16; s-split-4 partials) ----
            {
                const int dq = tid & 127, sg = tid >> 7;
                const uint2* ep = (const uint2*)(ECB + (size_t)b * 32768);
                float4 a = {0.f, 0.f, 0.f, 0.f};
                #pragma unroll 4
                for (int si = 0; si < 32; ++si) {
                    const int s = sg * 32 + si;
                    const float wgt = w_s[s];
                    const uint2 e2 = ep[(size_t)s * 128 + dq];
                    const float2 e0 = unpackbf2(e2.x), e1 = unpackbf2(e2.y);
                    a.x = fmaf(wgt, e0.x, a.x);
                    a.y = fmaf(wgt, e0.y, a.y);
                    a.z = fmaf(wgt, e1.x, a.z);
                    a.w = fmaf(wgt, e1.y, a.w);
                }
                ((float4*)psq)[sg * 128 + dq] = a;
            }
            __syncthreads();
            if (tid < 128) {
                const float4* p4 = (const float4*)psq;
                float4 a = p4[tid], b2 = p4[128 + tid], c2 = p4[256 + tid], d2 = p4[384 + tid];
                float4 rr;
                rr.x = a.x + b2.x + c2.x + d2.x;
                rr.y = a.y + b2.y + c2.y + d2.y;
                rr.z = a.z + b2.z + c2.z + d2.z;
                rr.w = a.w + b2.w + c2.w + d2.w;
                cstore64(CxS + (size_t)bl * 256 + tid * 2,     ((u64)tagv << 32) | (u64)packbf2(rr.x, rr.y));
                cstore64(CxS + (size_t)bl * 256 + tid * 2 + 1, ((u64)tagv << 32) | (u64)packbf2(rr.z, rr.w));
            }
        }

        // ---- final coords (needs H_64: slot 0, tag 64) ----
        if (tid < 256) {
            u64 vh = poll_tag(Hx + (size_t)bl * 256 + tid, 64u);
            ((float2*)h_s)[tid] = unpackbf2((u32)vh);
        }
        __syncthreads();
        {
            const float hv = h_s[tid];
            float p0 = hv * Wo_w[tid * 3 + 0];
            float p1 = hv * Wo_w[tid * 3 + 1];
            float p2 = hv * Wo_w[tid * 3 + 2];
            #pragma unroll
            for (int off = 32; off > 0; off >>= 1) {
                p0 += __shfl_down(p0, off);
                p1 += __shfl_down(p1, off);
                p2 += __shfl_down(p2, off);
            }
            if (lane == 0) { red[8 + wv * 3] = p0; red[8 + wv * 3 + 1] = p1; red[8 + wv * 3 + 2] = p2; }
            __syncthreads();
            if (tid < 3) {
                float s_ = Wo_b[tid];
                #pragma unroll
                for (int w2 = 0; w2 < 8; ++w2) s_ += red[8 + w2 * 3 + tid];
                out[((size_t)b * 64 + 63) * 3 + tid] = s_;
            }
        }
    } else {
        // ========== GRU block: 16 dims + 16 q-cols, all 16 b of its group ==========
        const int idx = r - 16, d0 = idx * 16, qc0 = idx * 16;
        float* hb_s = (float*)smraw;                // 16x512 fp32 = 32768 B (h, then ctx)
        float* gh_s = (float*)(smraw + 32768);      // 768
        float* gi_s = (float*)(smraw + 35840);      // 768
        float* x_s  = (float*)(smraw + 38912);      // 48
        float* wx_s = (float*)(smraw + 39168);      // 144
        float4* hb4 = (float4*)hb_s;

        const int i5 = tid >> 5, ks = tid & 31;     // dim-local, k-split
        // k mapping: k(j,c) = (j*32+ks)*4 + c  (conflict-free float4 LDS reads)
        float4 wq4[4], wh[3][4], wi[3][4];
        {
            const int col = qc0 + i5;
            #pragma unroll
            for (int j = 0; j < 4; ++j) {
                const int kb = (j * 32 + ks) * 4;
                wq4[j].x = Wa_w[(size_t)(kb + 0) * 512 + col];
                wq4[j].y = Wa_w[(size_t)(kb + 1) * 512 + col];
                wq4[j].z = Wa_w[(size_t)(kb + 2) * 512 + col];
                wq4[j].w = Wa_w[(size_t)(kb + 3) * 512 + col];
                #pragma unroll
                for (int g3 = 0; g3 < 3; ++g3) {
                    const int row = g3 * 512 + d0 + i5;
                    wh[g3][j] = *(const float4*)(W_hh + (size_t)row * 512 + kb);
                    const float* wir = W_ih + (size_t)row * 515 + kb;
                    wi[g3][j] = make_float4(wir[0], wir[1], wir[2], wir[3]);
                }
            }
        }
        const float qbias = Wa_b[qc0 + i5];
        float bhh[3];
        #pragma unroll
        for (int g3 = 0; g3 < 3; ++g3) bhh[g3] = b_hh[g3 * 512 + d0 + i5];
        if (tid < 144) {
            const int dd = tid / 9, rem = tid - dd * 9, g3 = rem / 3, c = rem - g3 * 3;
            wx_s[tid] = W_ih[(size_t)(g3 * 512 + d0 + dd) * 515 + 512 + c];
        }
        const int gb = tid >> 4, gd = tid & 15;     // gates mapping (tid<256)
        float hold = 0.f, bih[3];
        if (tid < 256) {
            hold = e_last[(size_t)(g * 16 + gb) * 512 + d0 + gd];
            #pragma unroll
            for (int g3 = 0; g3 < 3; ++g3) bih[g3] = b_ih[g3 * 512 + d0 + gd];
        }

        for (int t = 0; t < 64; ++t) {
            const u32 tagv = (u32)t;
            const int slot = t & 1, wslot = (t + 1) & 1;
            u64* HxS = Hx + slot * HX_SLOT;
            u64* CxS = Cx + slot * CX_SLOT;
            u64* QxS = Qx + slot * QX_SLOT;
            u64* XxS = Xx + slot * XX_SLOT;

            // ---- poll + stage h (bf16 -> fp32 LDS, b-major) ----
            {
                const u64* hp = HxS + tid * 8;
                u64 v[8];
                #pragma unroll
                for (int u = 0; u < 8; ++u) v[u] = cload64(hp + u);
                #pragma unroll
                for (int u = 0; u < 8; ++u)
                    while ((u32)(v[u] >> 32) != tagv) { __builtin_amdgcn_s_sleep(1); v[u] = cload64(hp + u); }
                #pragma unroll
                for (int u = 0; u < 8; ++u)
                    ((float2*)hb_s)[tid * 8 + u] = unpackbf2((u32)v[u]);
            }
            __syncthreads();

            // ---- q = h @ Wa (16 cols), write tagged ----
            {
                float acc[16];
                #pragma unroll
                for (int b2 = 0; b2 < 16; ++b2) acc[b2] = 0.f;
                #pragma unroll
                for (int j = 0; j < 4; ++j) {
                    const float4 w = wq4[j];
                    #pragma unroll
                    for (int b2 = 0; b2 < 16; ++b2) {
                        const float4 hv = hb4[b2 * 128 + j * 32 + ks];
                        acc[b2] = fmaf(hv.x, w.x, fmaf(hv.y, w.y, fmaf(hv.z, w.z, fmaf(hv.w, w.w, acc[b2]))));
                    }
                }
                #pragma unroll
                for (int off = 1; off < 32; off <<= 1) {
                    #pragma unroll
                    for (int b2 = 0; b2 < 16; ++b2) acc[b2] += __shfl_xor(acc[b2], off);
                }
                if (ks == 0) {
                    u64* qp = QxS + qc0 + i5;
                    #pragma unroll
                    for (int b2 = 0; b2 < 16; ++b2)
                        cstore64(qp + b2 * 512, ((u64)tagv << 32) | (u64)__float_as_uint(acc[b2] + qbias));
                }
            }

            // ---- gh = h @ W_hh^T (overlaps attention) ----
            {
                float aR[16], aZ[16], aN[16];
                #pragma unroll
                for (int b2 = 0; b2 < 16; ++b2) { aR[b2] = 0.f; aZ[b2] = 0.f; aN[b2] = 0.f; }
                #pragma unroll
                for (int j = 0; j < 4; ++j) {
                    const float4 w0 = wh[0][j], w1 = wh[1][j], w2 = wh[2][j];
                    #pragma unroll
                    for (int b2 = 0; b2 < 16; ++b2) {
                        const float4 hv = hb4[b2 * 128 + j * 32 + ks];
                        aR[b2] = fmaf(hv.x, w0.x, fmaf(hv.y, w0.y, fmaf(hv.z, w0.z, fmaf(hv.w, w0.w, aR[b2]))));
                        aZ[b2] = fmaf(hv.x, w1.x, fmaf(hv.y, w1.y, fmaf(hv.z, w1.z, fmaf(hv.w, w1.w, aZ[b2]))));
                        aN[b2] = fmaf(hv.x, w2.x, fmaf(hv.y, w2.y, fmaf(hv.z, w2.z, fmaf(hv.w, w2.w, aN[b2]))));
                    }
                }
                #pragma unroll
                for (int off = 1; off < 32; off <<= 1) {
                    #pragma unroll
                    for (int b2 = 0; b2 < 16; ++b2) {
                        aR[b2] += __shfl_xor(aR[b2], off);
                        aZ[b2] += __shfl_xor(aZ[b2], off);
                        aN[b2] += __shfl_xor(aN[b2], off);
                    }
                }
                if (ks == 0) {
                    #pragma unroll
                    for (int b2 = 0; b2 < 16; ++b2) {
                        const int ob = (b2 * 16 + i5) * 3;
                        gh_s[ob + 0] = aR[b2] + bhh[0];
                        gh_s[ob + 1] = aZ[b2] + bhh[1];
                        gh_s[ob + 2] = aN[b2] + bhh[2];
                    }
                }
            }
            __syncthreads();   // gh done; hb_s free for ctx

            // ---- poll + stage ctx; poll x ----
            {
                const u64* cp = CxS + tid * 8;
                u64 v[8];
                #pragma unroll
                for (int u = 0; u < 8; ++u) v[u] = cload64(cp + u);
                #pragma unroll
                for (int u = 0; u < 8; ++u)
                    while ((u32)(v[u] >> 32) != tagv) { __builtin_amdgcn_s_sleep(1); v[u] = cload64(cp + u); }
                #pragma unroll
                for (int u = 0; u < 8; ++u)
                    ((float2*)hb_s)[tid * 8 + u] = unpackbf2((u32)v[u]);
            }
            if (tid < 48) {
                if (t > 0) {
                    u64 vx = poll_tag(XxS + (tid / 3) * 4 + (tid % 3), tagv);
                    x_s[tid] = __uint_as_float((u32)vx);
                } else x_s[tid] = 0.f;
            }
            __syncthreads();

            // ---- gi = ctx @ W_ih^T (ctx part) ----
            {
                float aR[16], aZ[16], aN[16];
                #pragma unroll
                for (int b2 = 0; b2 < 16; ++b2) { aR[b2] = 0.f; aZ[b2] = 0.f; aN[b2] = 0.f; }
                #pragma unroll
                for (int j = 0; j < 4; ++j) {
                    const float4 w0 = wi[0][j], w1 = wi[1][j], w2 = wi[2][j];
                    #pragma unroll
                    for (int b2 = 0; b2 < 16; ++b2) {
                        const float4 hv = hb4[b2 * 128 + j * 32 + ks];
                        aR[b2] = fmaf(hv.x, w0.x, fmaf(hv.y, w0.y, fmaf(hv.z, w0.z, fmaf(hv.w, w0.w, aR[b2]))));
                        aZ[b2] = fmaf(hv.x, w1.x, fmaf(hv.y, w1.y, fmaf(hv.z, w1.z, fmaf(hv.w, w1.w, aZ[b2]))));
                        aN[b2] = fmaf(hv.x, w2.x, fmaf(hv.y, w2.y, fmaf(hv.z, w2.z, fmaf(hv.w, w2.w, aN[b2]))));
                    }
                }
                #pragma unroll
                for (int off = 1; off < 32; off <<= 1) {
                    #pragma unroll
                    for (int b2 = 0; b2 < 16; ++b2) {
                        aR[b2] += __shfl_xor(aR[b2], off);
                        aZ[b2] += __shfl_xor(aZ[b2], off);
                        aN[b2] += __shfl_xor(aN[b2], off);
                    }
                }
                if (ks == 0) {
                    #pragma unroll
                    for (int b2 = 0; b2 < 16; ++b2) {
                        const int ob = (b2 * 16 + i5) * 3;
                        gi_s[ob + 0] = aR[b2];
                        gi_s[ob + 1] = aZ[b2];
                        gi_s[ob + 2] = aN[b2];
                    }
                }
            }
            __syncthreads();

            // ---- gates + h update + tagged h write ----
            if (tid < 256) {
                const int ob = (gb * 16 + gd) * 3;
                const float x0 = x_s[gb * 3 + 0], x1 = x_s[gb * 3 + 1], x2 = x_s[gb * 3 + 2];
                float giR = gi_s[ob + 0] + bih[0]
                          + x0 * wx_s[gd * 9 + 0] + x1 * wx_s[gd * 9 + 1] + x2 * wx_s[gd * 9 + 2];
                float giZ = gi_s[ob + 1] + bih[1]
                          + x0 * wx_s[gd * 9 + 3] + x1 * wx_s[gd * 9 + 4] + x2 * wx_s[gd * 9 + 5];
                float giN = gi_s[ob + 2] + bih[2]
                          + x0 * wx_s[gd * 9 + 6] + x1 * wx_s[gd * 9 + 7] + x2 * wx_s[gd * 9 + 8];
                const float rg = sigm_f(giR + gh_s[ob + 0]);
                const float zg = sigm_f(giZ + gh_s[ob + 1]);
                const float ng = tanh_f(giN + rg * gh_s[ob + 2]);
                const float hnew = (1.f - zg) * ng + zg * hold;
                hold = hnew;
                const float hpair = __shfl_down(hnew, 1);
                if ((gd & 1) == 0)
                    cstore64(Hx + wslot * HX_SLOT + gb * 256 + ((d0 + gd) >> 1),
                             ((u64)(u32)(t + 1) << 32) | (u64)packbf2(hnew, hpair));
                if (t == 63)
                    out[OFF_OUT_HT + (size_t)(g * 16 + gb) * 512 + d0 + gd] = hnew;
            }
        }
    }
}

extern "C" void kernel_launch(void* const* d_in, const int* in_sizes, int n_in,
                              void* d_out, int out_size, void* d_ws, size_t ws_size,
                              hipStream_t stream) {
    const float* e_all  = (const float*)d_in[0];
    const float* e_last = (const float*)d_in[1];
    const float* Wa_w   = (const float*)d_in[2];
    const float* Wa_b   = (const float*)d_in[3];
    const float* Ua_w   = (const float*)d_in[4];
    const float* Ua_b   = (const float*)d_in[5];
    const float* Va_w   = (const float*)d_in[6];
    const float* W_ih   = (const float*)d_in[8];
    const float* W_hh   = (const float*)d_in[9];
    const float* b_ih   = (const float*)d_in[10];
    const float* b_hh   = (const float*)d_in[11];
    const float* Wo_w   = (const float*)d_in[12];
    const float* Wo_b   = (const float*)d_in[13];
    float* outp = (float*)d_out;
    float* ws   = (float*)d_ws;

    hipFuncSetAttribute((const void*)decode_kernel,
                        hipFuncAttributeMaxDynamicSharedMemorySize, DYN_LDS);

    hipLaunchKernelGGL(prep_kernel, dim3(512), dim3(256), 0, stream,
                       e_all, e_last, Ua_w, Ua_b, ws);

    void* args[] = { (void*)&e_last, (void*)&Wa_w, (void*)&Wa_b, (void*)&Va_w,
                     (void*)&W_ih, (void*)&W_hh, (void*)&b_ih, (void*)&b_hh,
                     (void*)&Wo_w, (void*)&Wo_b, (void*)&outp, (void*)&ws };
    hipError_t err = hipLaunchCooperativeKernel((void*)decode_kernel, dim3(NBLK), dim3(NTHR),
                                                args, DYN_LDS, stream);
    if (err != hipSuccess) {
        // fallback: 192 blocks x 96KB LDS -> 1 block/CU, co-resident on 256 CUs
        hipLaunchKernelGGL(decode_kernel, dim3(NBLK), dim3(NTHR), DYN_LDS, stream,
                           e_last, Wa_w, Wa_b, Va_w, W_ih, W_hh, b_ih, b_hh,
                           Wo_w, Wo_b, outp, ws);
    }
}

// Round 6
// 1451.761 us; speedup vs baseline: 6.6017x; 1.8325x over previous
//
#include <hip/hip_runtime.h>

typedef unsigned int u32;
typedef unsigned long long u64;
typedef float f32x4 __attribute__((ext_vector_type(4)));
typedef short short8 __attribute__((ext_vector_type(8)));

// B=64, S=128, D=512, T=64. 4 groups x 16 batches.
// ws byte offsets:
#define OFF_UKB 0u          // u32[64*128*256] bf16 Uk
#define OFF_ECB 8388608u    // u32[64*128*256] bf16 e_all
#define OFF_WAP 16777216u   // u32[512*256]    bf16 Wa (pair-packed along cols)
#define OFF_EX  17563648u   // per-group exchange
#define G_BYTES 73728u
// group layout: HX u64[2][2048] @0 | CX u64[2][2048] @32768 | FH u32 @65536 (32x64B) | FC @67584 (16x64B)

#define OFF_OUT_HT  12288u
#define OFF_OUT_ATT 45056u

#define NBLK 192
#define NTHR 512
#define DYN_LDS 98304

__device__ __forceinline__ float fast_rcp(float x) { return __builtin_amdgcn_rcpf(x); }
// tanh = 1 - 2/(e^{2x}+1): graceful at +/-inf (rcp(inf)=0), no clamps needed
__device__ __forceinline__ float tanh5(float x) {
    float e = __expf(2.f * x);
    return 1.f - 2.f * fast_rcp(e + 1.f);
}
__device__ __forceinline__ float sigm_f(float x) { return fast_rcp(1.f + __expf(-x)); }

__device__ __forceinline__ u32 packbf2(float a, float b) {
    u32 ua = __float_as_uint(a); ua += 0x7FFFu + ((ua >> 16) & 1u);
    u32 ub = __float_as_uint(b); ub += 0x7FFFu + ((ub >> 16) & 1u);
    return (ua >> 16) | (ub & 0xFFFF0000u);
}
__device__ __forceinline__ float2 unpackbf2(u32 u) {
    return make_float2(__uint_as_float(u << 16), __uint_as_float(u & 0xFFFF0000u));
}

// relaxed agent-scope accessors: per-access cache bypass, no cache-wide inv/wb
__device__ __forceinline__ u64 cload64(const u64* p) {
    return __hip_atomic_load(p, __ATOMIC_RELAXED, __HIP_MEMORY_SCOPE_AGENT);
}
__device__ __forceinline__ void cstore64(u64* p, u64 v) {
    __hip_atomic_store(p, v, __ATOMIC_RELAXED, __HIP_MEMORY_SCOPE_AGENT);
}
__device__ __forceinline__ u32 cload32(const u32* p) {
    return __hip_atomic_load(p, __ATOMIC_RELAXED, __HIP_MEMORY_SCOPE_AGENT);
}
__device__ __forceinline__ void cstore32(u32* p, u32 v) {
    __hip_atomic_store(p, v, __ATOMIC_RELAXED, __HIP_MEMORY_SCOPE_AGENT);
}

union U8 { u32 u[4]; uint4 q; short8 s; };

// ---------------- prep: Uk GEMM(bf16) + e_all/Wa bf16 pack + H0 + flags ----------------
__global__ __launch_bounds__(256) void prep_kernel(
    const float* __restrict__ e_all, const float* __restrict__ e_last,
    const float* __restrict__ Wa_w,
    const float* __restrict__ Ua_w,  const float* __restrict__ Ua_b,
    float* __restrict__ ws)
{
    u32* UKB = (u32*)((char*)ws + OFF_UKB);
    u32* ECB = (u32*)((char*)ws + OFF_ECB);
    u32* WaP = (u32*)((char*)ws + OFF_WAP);

    __shared__ float a_s[16 * 512];
    const int blk = blockIdx.x, tid = threadIdx.x;
    const int gtid = blk * 256 + tid, gstride = 512 * 256;

    // flags zero: 4 groups x 768 u32
    for (int i = gtid; i < 3072; i += gstride) {
        const int g = i / 768, j = i - g * 768;
        ((u32*)((char*)ws + OFF_EX + (size_t)g * G_BYTES + 65536))[j] = 0u;
    }

    const int r0 = blk * 16;
    for (int i = tid; i < 16 * 512; i += 256) a_s[i] = e_all[(size_t)r0 * 512 + i];
    __syncthreads();

    const int jj = tid & 63, sub = tid >> 6;
    const int rbase = sub * 4 * 512;
    for (int jo = 0; jo < 4; ++jo) {
        const int j0 = (jo * 64 + jj) * 2;
        float a0[4], a1[4];
        #pragma unroll
        for (int rr = 0; rr < 4; ++rr) { a0[rr] = 0.f; a1[rr] = 0.f; }
        const float* wp = Ua_w + j0;
        #pragma unroll 4
        for (int k = 0; k < 512; ++k) {
            const float w0 = wp[(size_t)k * 512];
            const float w1 = wp[(size_t)k * 512 + 1];
            #pragma unroll
            for (int rr = 0; rr < 4; ++rr) {
                const float hv = a_s[rbase + rr * 512 + k];
                a0[rr] = fmaf(w0, hv, a0[rr]);
                a1[rr] = fmaf(w1, hv, a1[rr]);
            }
        }
        const float bb0 = Ua_b[j0], bb1 = Ua_b[j0 + 1];
        #pragma unroll
        for (int rr = 0; rr < 4; ++rr) {
            const int row = r0 + sub * 4 + rr;
            UKB[(size_t)row * 256 + (j0 >> 1)] = packbf2(a0[rr] + bb0, a1[rr] + bb1);
        }
    }

    // e_all bf16 pack
    for (int i = gtid; i < 2097152; i += gstride)
        ECB[i] = packbf2(e_all[2 * i], e_all[2 * i + 1]);

    // Wa bf16 pack: WaP[k*256 + cp] = (Wa[k][2cp], Wa[k][2cp+1])
    for (int i = gtid; i < 131072; i += gstride) {
        const int k = i >> 8, cp = i & 255;
        WaP[i] = packbf2(Wa_w[(size_t)k * 512 + 2 * cp], Wa_w[(size_t)k * 512 + 2 * cp + 1]);
    }

    // H0 -> HX slot 0 (u64 = 4 bf16)
    for (int i = gtid; i < 8192; i += gstride) {
        const int g = i >> 11, i2 = i & 2047;
        const int b = i2 >> 7, d4 = i2 & 127;
        const float* ep = e_last + ((size_t)(g * 16 + b) * 512) + 4 * d4;
        u64* HX = (u64*)((char*)ws + OFF_EX + (size_t)g * G_BYTES);
        HX[i2] = (u64)packbf2(ep[0], ep[1]) | ((u64)packbf2(ep[2], ep[3]) << 32);
    }
}

// ---------------- persistent decode: per group 16 attn + 32 GRU blocks ----------------
__global__ __launch_bounds__(512, 1) void decode_kernel(
    const float* __restrict__ e_last,
    const float* __restrict__ Wa_b,  const float* __restrict__ Va_w,
    const float* __restrict__ W_ih,  const float* __restrict__ W_hh,
    const float* __restrict__ b_ih,  const float* __restrict__ b_hh,
    const float* __restrict__ Wo_w,  const float* __restrict__ Wo_b,
    float* __restrict__ out, float* __restrict__ ws)
{
    extern __shared__ char smraw[];

    const u32* UKB = (const u32*)((char*)ws + OFF_UKB);
    const u32* ECB = (const u32*)((char*)ws + OFF_ECB);
    const uint4* WaP4 = (const uint4*)((char*)ws + OFF_WAP);

    const int tid = threadIdx.x;
    const int bi  = blockIdx.x;
    const int g   = bi / 48, r = bi % 48;
    const int lane = tid & 63, wv = tid >> 6;

    char* gbase = (char*)ws + OFF_EX + (size_t)g * G_BYTES;
    u64* HX = (u64*)gbase;
    u64* CX = (u64*)(gbase + 32768);
    u32* FH = (u32*)(gbase + 65536);
    u32* FC = (u32*)(gbase + 67584);

    if (r < 16) {
        // ===================== attention block: one per b =====================
        const int bl = r, b = g * 16 + bl;
        float* h_s   = (float*)smraw;              // 512
        float* q_s   = (float*)(smraw + 2048);
        float* va_s  = (float*)(smraw + 4096);
        float* wab_s = (float*)(smraw + 6144);
        float* sc_s  = (float*)(smraw + 8192);     // 128
        float* w_s   = (float*)(smraw + 8704);     // 128
        float* red   = (float*)(smraw + 9216);     // 16
        float* psq   = (float*)(smraw + 9344);     // 4096 floats

        va_s[tid] = Va_w[tid];
        wab_s[tid] = Wa_b[tid];

        for (int t = 0; t < 64; ++t) {
            const int slot = t & 1;
            const u64* HxS = HX + slot * 2048;
            u64* CxS = CX + slot * 2048;

            if (tid < 32) { const u32* f = FH + tid * 16; while (cload32(f) < (u32)t) {} }
            __syncthreads();
            if (tid < 128) {
                u64 v = cload64(HxS + bl * 128 + tid);
                float2 lo = unpackbf2((u32)v), hi = unpackbf2((u32)(v >> 32));
                ((float4*)h_s)[tid] = make_float4(lo.x, lo.y, hi.x, hi.y);
            }
            __syncthreads();

            // ---- q = h @ Wa (bf16 weights, 8-col x 8-ksplit) ----
            {
                const int co = tid & 63, kc = tid >> 6;
                float acc[8];
                #pragma unroll
                for (int i = 0; i < 8; ++i) acc[i] = 0.f;
                const uint4* wp = WaP4 + (size_t)kc * 64 * 64 + co;
                #pragma unroll 8
                for (int it = 0; it < 64; ++it) {
                    const uint4 w = wp[it * 64];
                    const float hv = h_s[kc * 64 + it];
                    const float2 a0 = unpackbf2(w.x), a1 = unpackbf2(w.y);
                    const float2 a2 = unpackbf2(w.z), a3 = unpackbf2(w.w);
                    acc[0] = fmaf(hv, a0.x, acc[0]); acc[1] = fmaf(hv, a0.y, acc[1]);
                    acc[2] = fmaf(hv, a1.x, acc[2]); acc[3] = fmaf(hv, a1.y, acc[3]);
                    acc[4] = fmaf(hv, a2.x, acc[4]); acc[5] = fmaf(hv, a2.y, acc[5]);
                    acc[6] = fmaf(hv, a3.x, acc[6]); acc[7] = fmaf(hv, a3.y, acc[7]);
                }
                #pragma unroll
                for (int i = 0; i < 8; ++i) psq[kc * 512 + co * 8 + i] = acc[i];
            }
            __syncthreads();
            {
                float qv = wab_s[tid];
                #pragma unroll
                for (int k = 0; k < 8; ++k) qv += psq[k * 512 + tid];
                q_s[tid] = qv;
            }
            __syncthreads();

            // ---- scores: tanh(q + Uk) . Va (Uk bf16) ----
            {
                const int kl = lane & 15;
                float4 qa[4], qb[4], vaa[4], vab[4];
                const float4* q4 = (const float4*)q_s;
                const float4* v4 = (const float4*)va_s;
                #pragma unroll
                for (int it = 0; it < 4; ++it) {
                    qa[it] = q4[(it * 16 + kl) * 2];  qb[it] = q4[(it * 16 + kl) * 2 + 1];
                    vaa[it] = v4[(it * 16 + kl) * 2]; vab[it] = v4[(it * 16 + kl) * 2 + 1];
                }
                const int sbase = wv * 16 + (lane >> 4);
                #pragma unroll
                for (int sg = 0; sg < 4; ++sg) {
                    const int s = sbase + sg * 4;
                    const uint4* uk4 = (const uint4*)(UKB + ((size_t)b * 128 + s) * 256);
                    float acc = 0.f;
                    #pragma unroll
                    for (int it = 0; it < 4; ++it) {
                        const uint4 u = uk4[it * 16 + kl];
                        const float2 u0 = unpackbf2(u.x), u1 = unpackbf2(u.y);
                        const float2 u2 = unpackbf2(u.z), u3 = unpackbf2(u.w);
                        acc = fmaf(tanh5(qa[it].x + u0.x), vaa[it].x, acc);
                        acc = fmaf(tanh5(qa[it].y + u0.y), vaa[it].y, acc);
                        acc = fmaf(tanh5(qa[it].z + u1.x), vaa[it].z, acc);
                        acc = fmaf(tanh5(qa[it].w + u1.y), vaa[it].w, acc);
                        acc = fmaf(tanh5(qb[it].x + u2.x), vab[it].x, acc);
                        acc = fmaf(tanh5(qb[it].y + u2.y), vab[it].y, acc);
                        acc = fmaf(tanh5(qb[it].z + u3.x), vab[it].z, acc);
                        acc = fmaf(tanh5(qb[it].w + u3.y), vab[it].w, acc);
                    }
                    acc += __shfl_xor(acc, 1); acc += __shfl_xor(acc, 2);
                    acc += __shfl_xor(acc, 4); acc += __shfl_xor(acc, 8);
                    if (kl == 0) sc_s[s] = acc;   // Va_b: softmax-invariant
                }
            }
            __syncthreads();

            // ---- softmax ----
            if (tid < 64) {
                float mx = fmaxf(sc_s[tid], sc_s[tid + 64]);
                #pragma unroll
                for (int off = 32; off > 0; off >>= 1) mx = fmaxf(mx, __shfl_down(mx, off));
                if (tid == 0) red[0] = mx;
            }
            __syncthreads();
            if (tid < 128) w_s[tid] = __expf(sc_s[tid] - red[0]);
            __syncthreads();
            if (tid < 64) {
                float sm = w_s[tid] + w_s[tid + 64];
                #pragma unroll
                for (int off = 32; off > 0; off >>= 1) sm += __shfl_down(sm, off);
                if (tid == 0) red[1] = fast_rcp(sm);
            }
            __syncthreads();
            if (tid < 128) {
                const float wn = w_s[tid] * red[1];
                w_s[tid] = wn;
                out[OFF_OUT_ATT + ((size_t)b * 64 + t) * 128 + tid] = wn;
            }
            __syncthreads();

            // ---- ctx = w @ e_all[b] (bf16, s-split-4) ----
            {
                const int dq = tid & 127, sg = tid >> 7;
                const uint2* ep = (const uint2*)(ECB + (size_t)b * 32768);
                float4 a = {0.f, 0.f, 0.f, 0.f};
                #pragma unroll 4
                for (int si = 0; si < 32; ++si) {
                    const int s = sg * 32 + si;
                    const float wgt = w_s[s];
                    const uint2 e2 = ep[(size_t)s * 128 + dq];
                    const float2 e0 = unpackbf2(e2.x), e1 = unpackbf2(e2.y);
                    a.x = fmaf(wgt, e0.x, a.x);
                    a.y = fmaf(wgt, e0.y, a.y);
                    a.z = fmaf(wgt, e1.x, a.z);
                    a.w = fmaf(wgt, e1.y, a.w);
                }
                ((float4*)psq)[sg * 128 + dq] = a;
            }
            __syncthreads();
            if (tid < 128) {
                const float4* p4 = (const float4*)psq;
                float4 a = p4[tid], b2 = p4[128 + tid], c2 = p4[256 + tid], d2 = p4[384 + tid];
                const float rx = a.x + b2.x + c2.x + d2.x;
                const float ry = a.y + b2.y + c2.y + d2.y;
                const float rz = a.z + b2.z + c2.z + d2.z;
                const float rw = a.w + b2.w + c2.w + d2.w;
                cstore64(CxS + bl * 128 + tid,
                         (u64)packbf2(rx, ry) | ((u64)packbf2(rz, rw) << 32));
            }
            __syncthreads();
            if (tid == 0) cstore32(FC + bl * 16, (u32)(t + 1));
        }
    } else {
        // ========== GRU block: 16 dims, 16 b, MFMA tiles, weights in B-frag regs ==========
        const int idx = r - 16, d0 = idx * 16;
        u32*   hbu  = (u32*)smraw;                  // [16][260] bf16-pairs (padded)
        float* gh_s = (float*)(smraw + 16640);      // 768
        float* gi_s = (float*)(smraw + 19712);      // 768
        float* x_s  = (float*)(smraw + 22784);      // 48
        float* wx_s = (float*)(smraw + 22976);      // 144
        float* wo_s = (float*)(smraw + 23552);      // 1536 + 3

        const int mn = lane & 15, quad = lane >> 4;

        // ---- B-fragments: wv 0-2 = gh gates R,Z,N; wv 3-5 = gi gates ----
        short8 bfrag[16];
        if (wv < 3) {
            const float* wrow = W_hh + (size_t)(wv * 512 + d0 + mn) * 512;
            #pragma unroll
            for (int kb = 0; kb < 16; ++kb) {
                const int k0 = kb * 32 + quad * 8;
                U8 tpk;
                #pragma unroll
                for (int c = 0; c < 4; ++c)
                    tpk.u[c] = packbf2(wrow[k0 + 2 * c], wrow[k0 + 2 * c + 1]);
                bfrag[kb] = tpk.s;
            }
        } else if (wv < 6) {
            const float* wrow = W_ih + (size_t)((wv - 3) * 512 + d0 + mn) * 515;
            #pragma unroll
            for (int kb = 0; kb < 16; ++kb) {
                const int k0 = kb * 32 + quad * 8;
                U8 tpk;
                #pragma unroll
                for (int c = 0; c < 4; ++c)
                    tpk.u[c] = packbf2(wrow[k0 + 2 * c], wrow[k0 + 2 * c + 1]);
                bfrag[kb] = tpk.s;
            }
        }
        if (tid < 144) {
            const int dd = tid / 9, rem = tid - dd * 9, g3 = rem / 3, c = rem - g3 * 3;
            wx_s[tid] = W_ih[(size_t)(g3 * 512 + d0 + dd) * 515 + 512 + c];
        }
        for (int i = tid; i < 1536; i += 512) wo_s[i] = Wo_w[i];
        if (tid < 3) wo_s[1536 + tid] = Wo_b[tid];

        const int gb = tid >> 4, gd = tid & 15;     // gates mapping (tid<256)
        float hold = 0.f, bih[3], bhh[3];
        if (tid < 256) {
            hold = e_last[(size_t)(g * 16 + gb) * 512 + d0 + gd];
            #pragma unroll
            for (int g3 = 0; g3 < 3; ++g3) {
                bih[g3] = b_ih[g3 * 512 + d0 + gd];
                bhh[g3] = b_hh[g3 * 512 + d0 + gd];
            }
        }

        for (int t = 0; t < 64; ++t) {
            const int slot = t & 1;
            const u64* HxS = HX + slot * 2048;
            const u64* CxS = CX + slot * 2048;
            u64* HxW = HX + ((t + 1) & 1) * 2048;

            if (tid < 32) { const u32* f = FH + tid * 16; while (cload32(f) < (u32)t) {} }
            __syncthreads();
            // stage h (raw bf16 pairs) into padded LDS
            #pragma unroll
            for (int u = 0; u < 4; ++u) {
                const int i = tid + 512 * u;
                const u64 v = cload64(HxS + i);
                *(u64*)(hbu + (i >> 7) * 260 + (i & 127) * 2) = v;
            }
            __syncthreads();

            // ---- gh MFMA (waves 0-2) | coords x_{t-1} (waves 6-7) ----
            if (wv < 3) {
                f32x4 c = {0.f, 0.f, 0.f, 0.f};
                #pragma unroll
                for (int kb = 0; kb < 16; ++kb) {
                    U8 a; a.q = *(const uint4*)(hbu + mn * 260 + kb * 16 + quad * 4);
                    c = __builtin_amdgcn_mfma_f32_16x16x32_bf16(a.s, bfrag[kb], c, 0, 0, 0);
                }
                #pragma unroll
                for (int reg = 0; reg < 4; ++reg)
                    gh_s[((quad * 4 + reg) * 16 + mn) * 3 + wv] = c[reg];
            } else if (wv >= 6) {
                const int tt = tid - 384, cb = tt >> 3, kl = tt & 7;
                if (t > 0) {
                    float a0 = 0.f, a1 = 0.f, a2 = 0.f;
                    #pragma unroll 4
                    for (int c = 0; c < 32; ++c) {
                        const int p = kl * 32 + c;
                        const float2 hv = unpackbf2(hbu[cb * 260 + p]);
                        const float* w0 = wo_s + 2 * p * 3;
                        a0 = fmaf(hv.x, w0[0], fmaf(hv.y, w0[3], a0));
                        a1 = fmaf(hv.x, w0[1], fmaf(hv.y, w0[4], a1));
                        a2 = fmaf(hv.x, w0[2], fmaf(hv.y, w0[5], a2));
                    }
                    a0 += __shfl_xor(a0, 1); a1 += __shfl_xor(a1, 1); a2 += __shfl_xor(a2, 1);
                    a0 += __shfl_xor(a0, 2); a1 += __shfl_xor(a1, 2); a2 += __shfl_xor(a2, 2);
                    a0 += __shfl_xor(a0, 4); a1 += __shfl_xor(a1, 4); a2 += __shfl_xor(a2, 4);
                    if (kl == 0) {
                        x_s[cb * 3 + 0] = a0 + wo_s[1536];
                        x_s[cb * 3 + 1] = a1 + wo_s[1537];
                        x_s[cb * 3 + 2] = a2 + wo_s[1538];
                    }
                } else if (tt < 48) x_s[tt] = 0.f;
            }

            // ---- poll ctx ----
            if (tid < 16) { const u32* f = FC + tid * 16; while (cload32(f) < (u32)(t + 1)) {} }
            __syncthreads();   // guards gh_s/x_s writes + hbu reuse

            if (idx == 0 && t > 0 && tid < 48)
                out[((size_t)(g * 16 + tid / 3) * 64 + (t - 1)) * 3 + tid % 3] = x_s[tid];

            // stage ctx into hbu
            #pragma unroll
            for (int u = 0; u < 4; ++u) {
                const int i = tid + 512 * u;
                const u64 v = cload64(CxS + i);
                *(u64*)(hbu + (i >> 7) * 260 + (i & 127) * 2) = v;
            }
            __syncthreads();

            // ---- gi MFMA (waves 3-5) ----
            if (wv >= 3 && wv < 6) {
                f32x4 c = {0.f, 0.f, 0.f, 0.f};
                #pragma unroll
                for (int kb = 0; kb < 16; ++kb) {
                    U8 a; a.q = *(const uint4*)(hbu + mn * 260 + kb * 16 + quad * 4);
                    c = __builtin_amdgcn_mfma_f32_16x16x32_bf16(a.s, bfrag[kb], c, 0, 0, 0);
                }
                #pragma unroll
                for (int reg = 0; reg < 4; ++reg)
                    gi_s[((quad * 4 + reg) * 16 + mn) * 3 + (wv - 3)] = c[reg];
            }
            __syncthreads();

            // ---- gates + h update ----
            if (tid < 256) {
                const int ob = (gb * 16 + gd) * 3;
                const float x0 = x_s[gb * 3 + 0], x1 = x_s[gb * 3 + 1], x2 = x_s[gb * 3 + 2];
                const float giR = gi_s[ob + 0] + bih[0]
                                + x0 * wx_s[gd * 9 + 0] + x1 * wx_s[gd * 9 + 1] + x2 * wx_s[gd * 9 + 2];
                const float giZ = gi_s[ob + 1] + bih[1]
                                + x0 * wx_s[gd * 9 + 3] + x1 * wx_s[gd * 9 + 4] + x2 * wx_s[gd * 9 + 5];
                const float giN = gi_s[ob + 2] + bih[2]
                                + x0 * wx_s[gd * 9 + 6] + x1 * wx_s[gd * 9 + 7] + x2 * wx_s[gd * 9 + 8];
                const float ghR = gh_s[ob + 0] + bhh[0];
                const float ghZ = gh_s[ob + 1] + bhh[1];
                const float ghN = gh_s[ob + 2] + bhh[2];
                const float rg = sigm_f(giR + ghR);
                const float zg = sigm_f(giZ + ghZ);
                const float ng = tanh5(giN + rg * ghN);
                const float hnew = (1.f - zg) * ng + zg * hold;
                hold = hnew;
                const float s1 = __shfl_down(hnew, 1);
                const float s2 = __shfl_down(hnew, 2);
                const float s3 = __shfl_down(hnew, 3);
                if ((gd & 3) == 0)
                    cstore64(HxW + gb * 128 + ((d0 + gd) >> 2),
                             (u64)packbf2(hnew, s1) | ((u64)packbf2(s2, s3) << 32));
                if (t == 63)
                    out[OFF_OUT_HT + (size_t)(g * 16 + gb) * 512 + d0 + gd] = hnew;
            }
            __syncthreads();
            if (tid == 0) cstore32(FH + idx * 16, (u32)(t + 1));
        }

        // ---- final: coords(h_64) -> out[:,63] ----
        if (tid < 32) { const u32* f = FH + tid * 16; while (cload32(f) < 64u) {} }
        __syncthreads();
        #pragma unroll
        for (int u = 0; u < 4; ++u) {
            const int i = tid + 512 * u;
            const u64 v = cload64(HX + i);   // slot 0 holds h_64
            *(u64*)(hbu + (i >> 7) * 260 + (i & 127) * 2) = v;
        }
        __syncthreads();
        if (wv >= 6) {
            const int tt = tid - 384, cb = tt >> 3, kl = tt & 7;
            float a0 = 0.f, a1 = 0.f, a2 = 0.f;
            #pragma unroll 4
            for (int c = 0; c < 32; ++c) {
                const int p = kl * 32 + c;
                const float2 hv = unpackbf2(hbu[cb * 260 + p]);
                const float* w0 = wo_s + 2 * p * 3;
                a0 = fmaf(hv.x, w0[0], fmaf(hv.y, w0[3], a0));
                a1 = fmaf(hv.x, w0[1], fmaf(hv.y, w0[4], a1));
                a2 = fmaf(hv.x, w0[2], fmaf(hv.y, w0[5], a2));
            }
            a0 += __shfl_xor(a0, 1); a1 += __shfl_xor(a1, 1); a2 += __shfl_xor(a2, 1);
            a0 += __shfl_xor(a0, 2); a1 += __shfl_xor(a1, 2); a2 += __shfl_xor(a2, 2);
            a0 += __shfl_xor(a0, 4); a1 += __shfl_xor(a1, 4); a2 += __shfl_xor(a2, 4);
            if (kl == 0) {
                x_s[cb * 3 + 0] = a0 + wo_s[1536];
                x_s[cb * 3 + 1] = a1 + wo_s[1537];
                x_s[cb * 3 + 2] = a2 + wo_s[1538];
            }
        }
        __syncthreads();
        if (idx == 0 && tid < 48)
            out[((size_t)(g * 16 + tid / 3) * 64 + 63) * 3 + tid % 3] = x_s[tid];
    }
}

extern "C" void kernel_launch(void* const* d_in, const int* in_sizes, int n_in,
                              void* d_out, int out_size, void* d_ws, size_t ws_size,
                              hipStream_t stream) {
    const float* e_all  = (const float*)d_in[0];
    const float* e_last = (const float*)d_in[1];
    const float* Wa_w   = (const float*)d_in[2];
    const float* Wa_b   = (const float*)d_in[3];
    const float* Ua_w   = (const float*)d_in[4];
    const float* Ua_b   = (const float*)d_in[5];
    const float* Va_w   = (const float*)d_in[6];
    const float* W_ih   = (const float*)d_in[8];
    const float* W_hh   = (const float*)d_in[9];
    const float* b_ih   = (const float*)d_in[10];
    const float* b_hh   = (const float*)d_in[11];
    const float* Wo_w   = (const float*)d_in[12];
    const float* Wo_b   = (const float*)d_in[13];
    float* outp = (float*)d_out;
    float* ws   = (float*)d_ws;

    hipFuncSetAttribute((const void*)decode_kernel,
                        hipFuncAttributeMaxDynamicSharedMemorySize, DYN_LDS);

    hipLaunchKernelGGL(prep_kernel, dim3(512), dim3(256), 0, stream,
                       e_all, e_last, Wa_w, Ua_w, Ua_b, ws);

    void* args[] = { (void*)&e_last, (void*)&Wa_b, (void*)&Va_w,
                     (void*)&W_ih, (void*)&W_hh, (void*)&b_ih, (void*)&b_hh,
                     (void*)&Wo_w, (void*)&Wo_b, (void*)&outp, (void*)&ws };
    hipError_t err = hipLaunchCooperativeKernel((void*)decode_kernel, dim3(NBLK), dim3(NTHR),
                                                args, DYN_LDS, stream);
    if (err != hipSuccess) {
        // fallback: 192 blocks x 96KB LDS -> 1 block/CU, co-resident on 256 CUs
        hipLaunchKernelGGL(decode_kernel, dim3(NBLK), dim3(NTHR), DYN_LDS, stream,
                           e_last, Wa_b, Va_w, W_ih, W_hh, b_ih, b_hh,
                           Wo_w, Wo_b, outp, ws);
    }
}